// Round 17
// baseline (2164.219 us; speedup 1.0000x reference)
//
#include <hip/hip_runtime.h>

#define NN 1000000
#define NE 4000000
#define NG 25000
#define BN_EPS 1e-5f

typedef unsigned short u16t;
typedef unsigned int u32t;
typedef __attribute__((ext_vector_type(8))) short bf16x8;
typedef __attribute__((ext_vector_type(8))) _Float16 f16x8;
typedef __attribute__((ext_vector_type(4))) float f32x4;

__device__ inline u16t f2bf(float f) {
  u32t u = __float_as_uint(f);
  u32t r = (u + 0x7FFFu + ((u >> 16) & 1u)) >> 16;
  return (u16t)r;
}
__device__ inline float bf2f(u16t h) { return __uint_as_float((u32t)h << 16); }
__device__ inline u16t f2h(float f) {
  _Float16 h = (_Float16)f;
  return *(u16t*)&h;
}
__device__ inline float h2f(u16t v) {
  _Float16 h = *(_Float16*)&v;
  return (float)h;
}
__device__ inline void add8h(float* a, uint4 v) {
  union { uint4 u; _Float16 h[8]; } cv;
  cv.u = v;
#pragma unroll
  for (int j = 0; j < 8; ++j) a[j] += (float)cv.h[j];
}

// ---- workspace layout (bytes) ----
static const size_t OFF_U    = 0;
static const size_t OFF_T3   = 0;
static const size_t OFF_YA   = 150000000;
static const size_t OFF_YB   = 214000000;
static const size_t OFF_ST   = 278000000;
static const size_t OFF_RS   = 279000000;
static const size_t OFF_CUR  = 283200000;
static const size_t OFF_BSUM = 287300000;
static const size_t OFF_SSRC = 288000000;
static const size_t OFF_WK   = 304000000;
static const size_t OFF_XC   = 306000000;
static const size_t OFF_H1   = 150000000;
static const size_t OFF_H2   = 214000000;

// ---------------- CSR build ----------------
__global__ __launch_bounds__(256) void k_hist(const int* __restrict__ ei, u32t* __restrict__ cnt) {
  const int i = blockIdx.x * 256 + threadIdx.x;
  if (i < NE) atomicAdd(&cnt[ei[NE + i]], 1u);
}

__global__ __launch_bounds__(256) void k_scan1(const u32t* __restrict__ deg, u32t* __restrict__ bsum) {
  __shared__ u32t red[4];
  const int b = blockIdx.x, t = threadIdx.x;
  u32t s = 0;
#pragma unroll
  for (int j = 0; j < 4; ++j) {
    const int i = b * 1024 + j * 256 + t;
    if (i < NN) s += deg[i];
  }
#pragma unroll
  for (int off = 32; off > 0; off >>= 1) s += __shfl_down(s, off);
  if ((t & 63) == 0) red[t >> 6] = s;
  __syncthreads();
  if (t == 0) bsum[b] = red[0] + red[1] + red[2] + red[3];
}

__global__ __launch_bounds__(256) void k_scan2(u32t* __restrict__ bsum, u32t* __restrict__ rs, int nblk) {
  __shared__ u32t sh[256];
  const int t = threadIdx.x;
  u32t v[4];
#pragma unroll
  for (int j = 0; j < 4; ++j) {
    const int i = t * 4 + j;
    v[j] = (i < nblk) ? bsum[i] : 0u;
  }
  const u32t tot = v[0] + v[1] + v[2] + v[3];
  sh[t] = tot;
  __syncthreads();
  for (int off = 1; off < 256; off <<= 1) {
    u32t add = (t >= off) ? sh[t - off] : 0u;
    __syncthreads();
    sh[t] += add;
    __syncthreads();
  }
  const u32t tb = (t == 0) ? 0u : sh[t - 1];
  u32t run = tb;
#pragma unroll
  for (int j = 0; j < 4; ++j) {
    const int i = t * 4 + j;
    if (i < nblk) bsum[i] = run;
    run += v[j];
  }
  if (t == 0) rs[NN] = NE;
}

__global__ __launch_bounds__(256) void k_scan3(u32t* __restrict__ cur, u32t* __restrict__ rs,
                                               const u32t* __restrict__ bsum) {
  __shared__ u32t sh[256];
  const int b = blockIdx.x, t = threadIdx.x;
  const int i0 = b * 1024 + t * 4;
  u32t v[4];
#pragma unroll
  for (int j = 0; j < 4; ++j) v[j] = (i0 + j < NN) ? cur[i0 + j] : 0u;
  sh[t] = v[0] + v[1] + v[2] + v[3];
  __syncthreads();
  for (int off = 1; off < 256; off <<= 1) {
    u32t add = (t >= off) ? sh[t - off] : 0u;
    __syncthreads();
    sh[t] += add;
    __syncthreads();
  }
  u32t run = bsum[b] + ((t == 0) ? 0u : sh[t - 1]);
#pragma unroll
  for (int j = 0; j < 4; ++j) {
    const int i = i0 + j;
    if (i < NN) { rs[i] = run; cur[i] = run; }
    run += v[j];
  }
}

// dst-range-partitioned scatter: pass p handles dst>>18 == p (4 passes).
// Each pass's ssrc writes land in a ~4MB contiguous window -> L2 merges sectors.
__global__ __launch_bounds__(256) void k_scatter(const int* __restrict__ ei,
                                                 u32t* __restrict__ cur, int* __restrict__ ssrc,
                                                 int pass) {
  const int i = blockIdx.x * 256 + threadIdx.x;
  if (i < NE) {
    const int dst = ei[NE + i];
    if ((dst >> 18) == pass) {
      const int src = ei[i];
      const u32t pos = atomicAdd(&cur[dst], 1u);
      ssrc[pos] = src;
    }
  }
}

// ---------------- GNN kernels ----------------

__global__ __launch_bounds__(256) void k_mlp1_first(
    const float* __restrict__ x, const float* __restrict__ W1, u16t* __restrict__ u)
{
  __shared__ __align__(16) u16t Xh[64 * 104];
  __shared__ __align__(16) u16t Wt[32 * 104];
  __shared__ __align__(16) u16t Uh[64 * 40];
  const int t = threadIdx.x;
  const int n0b = blockIdx.x * 64;
  for (int id = t; id < 64 * 78; id += 256) {
    const int row = id / 78, k = id - row * 78;
    Xh[row * 104 + k] = f2h(x[(size_t)n0b * 78 + id]);
  }
  for (int id = t; id < 64 * 18; id += 256) {
    const int row = id / 18, k = 78 + (id - row * 18);
    Xh[row * 104 + k] = 0;
  }
  for (int id = t; id < 78 * 32; id += 256) {
    const int k = id >> 5, c = id & 31;
    Wt[c * 104 + k] = f2h(W1[id]);
  }
  for (int id = t; id < 32 * 18; id += 256) {
    const int c = id / 18, k = 78 + (id - c * 18);
    Wt[c * 104 + k] = 0;
  }
  __syncthreads();
  {
    const int w = t >> 6, l = t & 63, col = l & 15, kg = l >> 4;
    const int m0 = w * 16;
    f32x4 ac0 = {0.f, 0.f, 0.f, 0.f}, ac1 = {0.f, 0.f, 0.f, 0.f};
#pragma unroll
    for (int ks = 0; ks < 3; ++ks) {
      const f16x8 af = *(const f16x8*)(Xh + (m0 + col) * 104 + ks * 32 + kg * 8);
      const f16x8 bf0 = *(const f16x8*)(Wt + col * 104 + ks * 32 + kg * 8);
      const f16x8 bf1 = *(const f16x8*)(Wt + (16 + col) * 104 + ks * 32 + kg * 8);
      ac0 = __builtin_amdgcn_mfma_f32_16x16x32_f16(af, bf0, ac0, 0, 0, 0);
      ac1 = __builtin_amdgcn_mfma_f32_16x16x32_f16(af, bf1, ac1, 0, 0, 0);
    }
#pragma unroll
    for (int r = 0; r < 4; ++r) {
      const int m = m0 + kg * 4 + r;
      Uh[m * 40 + col] = f2h(ac0[r]);
      Uh[m * 40 + 16 + col] = f2h(ac1[r]);
    }
  }
  __syncthreads();
  {
    const int row = t >> 2;
    const uint4 v = *(const uint4*)(Uh + row * 40 + (t & 3) * 8);
    *(uint4*)(u + (size_t)(n0b + row) * 32 + (t & 3) * 8) = v;
  }
}

__global__ __launch_bounds__(256) void k_agg0(
    const u16t* __restrict__ u, const u32t* __restrict__ rs, const int* __restrict__ ssrc,
    const float* __restrict__ b1, const float* __restrict__ W2, const float* __restrict__ b2,
    u16t* __restrict__ yout, float* __restrict__ stats_out)
{
  __shared__ __align__(16) u16t W2t[32 * 40];
  __shared__ __align__(16) u16t A1h[64 * 40];
  __shared__ __align__(16) u16t A2h[64 * 40];
  __shared__ float red[256];
  __shared__ u32t rss[65];
  const int t = threadIdx.x;
  const int n0b = blockIdx.x * 64;
  for (int id = t; id < 1024; id += 256) {
    int k = id >> 5, c = id & 31;
    W2t[c * 40 + k] = f2h(W2[id]);
  }
  if (t < 65) rss[t] = rs[n0b + t];
  __syncthreads();
  const int nl = t >> 2, c0 = (t & 3) * 8;
  {
    const int n = n0b + nl;
    float a[8] = {};
    add8h(a, *(const uint4*)(u + (size_t)n * 32 + c0));
    const u32t e0 = rss[nl], e1 = rss[nl + 1];
    u32t e = e0;
    for (; e + 4 <= e1; e += 4) {
      const int s0v = ssrc[e], s1v = ssrc[e + 1], s2v = ssrc[e + 2], s3v = ssrc[e + 3];
      const uint4 v0 = *(const uint4*)(u + (size_t)s0v * 32 + c0);
      const uint4 v1 = *(const uint4*)(u + (size_t)s1v * 32 + c0);
      const uint4 v2 = *(const uint4*)(u + (size_t)s2v * 32 + c0);
      const uint4 v3 = *(const uint4*)(u + (size_t)s3v * 32 + c0);
      add8h(a, v0); add8h(a, v1); add8h(a, v2); add8h(a, v3);
    }
    for (; e < e1; ++e)
      add8h(a, *(const uint4*)(u + (size_t)ssrc[e] * 32 + c0));
    union { u16t h[8]; uint4 v; } pk;
#pragma unroll
    for (int j = 0; j < 8; ++j) pk.h[j] = f2h(fmaxf(a[j] + b1[c0 + j], 0.f));
    *(uint4*)(A1h + nl * 40 + c0) = pk.v;
  }
  __syncthreads();
  {
    const int w = t >> 6, l = t & 63, col = l & 15, kg = l >> 4;
    const int m0 = w * 16;
    const f16x8 af = *(const f16x8*)(A1h + (m0 + col) * 40 + kg * 8);
    const f16x8 bf0 = *(const f16x8*)(W2t + col * 40 + kg * 8);
    const f16x8 bf1 = *(const f16x8*)(W2t + (16 + col) * 40 + kg * 8);
    f32x4 ac0 = {0.f, 0.f, 0.f, 0.f}, ac1 = {0.f, 0.f, 0.f, 0.f};
    ac0 = __builtin_amdgcn_mfma_f32_16x16x32_f16(af, bf0, ac0, 0, 0, 0);
    ac1 = __builtin_amdgcn_mfma_f32_16x16x32_f16(af, bf1, ac1, 0, 0, 0);
    const float bb0 = b2[col], bb1 = b2[16 + col];
#pragma unroll
    for (int r = 0; r < 4; ++r) {
      const int m = m0 + kg * 4 + r;
      A2h[m * 40 + col] = f2h(fmaxf(ac0[r] + bb0, 0.f));
      A2h[m * 40 + 16 + col] = f2h(fmaxf(ac1[r] + bb1, 0.f));
    }
  }
  __syncthreads();
  const int c = t & 31;
  float rsum = 0.f, rq = 0.f;
#pragma unroll
  for (int rep = 0; rep < 8; ++rep) {
    const int row = (t >> 5) + rep * 8;
    const float v = h2f(A2h[row * 40 + c]);
    rsum += v;
    rq += v * v;
  }
  {
    const int row = t >> 2;
    const uint4 v = *(const uint4*)(A2h + row * 40 + (t & 3) * 8);
    *(uint4*)(yout + (size_t)(n0b + row) * 32 + (t & 3) * 8) = v;
  }
  rsum += __shfl_down(rsum, 32);
  rq += __shfl_down(rq, 32);
  __syncthreads();
  const int wv_ = t >> 6, lane = t & 63;
  if (lane < 32) {
    red[wv_ * 32 + lane] = rsum;
    red[128 + wv_ * 32 + lane] = rq;
  }
  __syncthreads();
  if (t < 32) {
    float aa = red[t] + red[32 + t] + red[64 + t] + red[96 + t];
    float bb = red[128 + t] + red[160 + t] + red[192 + t] + red[224 + t];
    unsafeAtomicAdd(&stats_out[t], aa);
    unsafeAtomicAdd(&stats_out[32 + t], bb);
  }
}

// ---- layer body (layers 1..4) ----
__device__ __forceinline__ void layer_body(
    int bid, char* smem,
    const u16t* __restrict__ yin, const u32t* __restrict__ rs, const int* __restrict__ ssrc,
    const float* __restrict__ stats, const float* __restrict__ gamma, const float* __restrict__ beta,
    const float* __restrict__ W1, const float* __restrict__ b1,
    const float* __restrict__ W2, const float* __restrict__ b2,
    u16t* __restrict__ yout, float* __restrict__ stats_out)
{
  u16t* W1t = (u16t*)smem;
  u16t* W2t = (u16t*)(smem + 2560);
  u16t* A1h = (u16t*)(smem + 5120);
  u16t* A2h = (u16t*)(smem + 10240);
  float* red = (float*)(smem + 15360);
  u32t* rss = (u32t*)(smem + 16384);
  const int t = threadIdx.x;
  const int n0b = bid * 64;
  for (int id = t; id < 1024; id += 256) {
    int k = id >> 5, c = id & 31;
    W1t[c * 40 + k] = f2h(W1[id]);
    W2t[c * 40 + k] = f2h(W2[id]);
  }
  if (t < 65) rss[t] = rs[n0b + t];
  __syncthreads();
  const int nl = t >> 2, c0 = (t & 3) * 8;
  {
    const int n = n0b + nl;
    float sc[8], sh[8];
#pragma unroll
    for (int j = 0; j < 8; ++j) {
      const int c = c0 + j;
      const float mu = stats[c] * (1.f / NN);
      float var = fmaxf(stats[32 + c] * (1.f / NN) - mu * mu, 0.f);
      sc[j] = gamma[c] * rsqrtf(var + BN_EPS);
      sh[j] = beta[c] - mu * sc[j];
    }
    float a[8] = {};
    add8h(a, *(const uint4*)(yin + (size_t)n * 32 + c0));
    const u32t e0 = rss[nl], e1 = rss[nl + 1];
    u32t e = e0;
    for (; e + 4 <= e1; e += 4) {
      const int s0v = ssrc[e], s1v = ssrc[e + 1], s2v = ssrc[e + 2], s3v = ssrc[e + 3];
      const uint4 v0 = *(const uint4*)(yin + (size_t)s0v * 32 + c0);
      const uint4 v1 = *(const uint4*)(yin + (size_t)s1v * 32 + c0);
      const uint4 v2 = *(const uint4*)(yin + (size_t)s2v * 32 + c0);
      const uint4 v3 = *(const uint4*)(yin + (size_t)s3v * 32 + c0);
      add8h(a, v0); add8h(a, v1); add8h(a, v2); add8h(a, v3);
    }
    for (; e < e1; ++e)
      add8h(a, *(const uint4*)(yin + (size_t)ssrc[e] * 32 + c0));
    const float cnt = (float)(e1 - e0 + 1u);
    union { u16t h[8]; uint4 v; } pk;
#pragma unroll
    for (int j = 0; j < 8; ++j) pk.h[j] = f2h(sc[j] * a[j] + cnt * sh[j]);
    *(uint4*)(A1h + nl * 40 + c0) = pk.v;
  }
  __syncthreads();
  const int w = t >> 6, l = t & 63, col = l & 15, kg = l >> 4;
  const int m0 = w * 16;
  {
    const f16x8 af = *(const f16x8*)(A1h + (m0 + col) * 40 + kg * 8);
    const f16x8 bf0 = *(const f16x8*)(W1t + col * 40 + kg * 8);
    const f16x8 bf1 = *(const f16x8*)(W1t + (16 + col) * 40 + kg * 8);
    f32x4 ac0 = {0.f, 0.f, 0.f, 0.f}, ac1 = {0.f, 0.f, 0.f, 0.f};
    ac0 = __builtin_amdgcn_mfma_f32_16x16x32_f16(af, bf0, ac0, 0, 0, 0);
    ac1 = __builtin_amdgcn_mfma_f32_16x16x32_f16(af, bf1, ac1, 0, 0, 0);
    const float bb0 = b1[col], bb1 = b1[16 + col];
#pragma unroll
    for (int r = 0; r < 4; ++r) {
      const int m = m0 + kg * 4 + r;
      A2h[m * 40 + col] = f2h(fmaxf(ac0[r] + bb0, 0.f));
      A2h[m * 40 + 16 + col] = f2h(fmaxf(ac1[r] + bb1, 0.f));
    }
  }
  __syncthreads();
  {
    const f16x8 af = *(const f16x8*)(A2h + (m0 + col) * 40 + kg * 8);
    const f16x8 bf0 = *(const f16x8*)(W2t + col * 40 + kg * 8);
    const f16x8 bf1 = *(const f16x8*)(W2t + (16 + col) * 40 + kg * 8);
    f32x4 ac0 = {0.f, 0.f, 0.f, 0.f}, ac1 = {0.f, 0.f, 0.f, 0.f};
    ac0 = __builtin_amdgcn_mfma_f32_16x16x32_f16(af, bf0, ac0, 0, 0, 0);
    ac1 = __builtin_amdgcn_mfma_f32_16x16x32_f16(af, bf1, ac1, 0, 0, 0);
    const float bb0 = b2[col], bb1 = b2[16 + col];
#pragma unroll
    for (int r = 0; r < 4; ++r) {
      const int m = m0 + kg * 4 + r;
      A1h[m * 40 + col] = f2h(fmaxf(ac0[r] + bb0, 0.f));
      A1h[m * 40 + 16 + col] = f2h(fmaxf(ac1[r] + bb1, 0.f));
    }
  }
  __syncthreads();
  const int c = t & 31;
  float rsum = 0.f, rq = 0.f;
#pragma unroll
  for (int rep = 0; rep < 8; ++rep) {
    const int row = (t >> 5) + rep * 8;
    const float v = h2f(A1h[row * 40 + c]);
    rsum += v;
    rq += v * v;
  }
  {
    const int row = t >> 2;
    const uint4 v = *(const uint4*)(A1h + row * 40 + (t & 3) * 8);
    *(uint4*)(yout + (size_t)(n0b + row) * 32 + (t & 3) * 8) = v;
  }
  rsum += __shfl_down(rsum, 32);
  rq += __shfl_down(rq, 32);
  __syncthreads();
  const int wv_ = t >> 6, lane = t & 63;
  if (lane < 32) {
    red[wv_ * 32 + lane] = rsum;
    red[128 + wv_ * 32 + lane] = rq;
  }
  __syncthreads();
  if (t < 32) {
    float aa = red[t] + red[32 + t] + red[64 + t] + red[96 + t];
    float bb = red[128 + t] + red[160 + t] + red[192 + t] + red[224 + t];
    unsafeAtomicAdd(&stats_out[t], aa);
    unsafeAtomicAdd(&stats_out[32 + t], bb);
  }
}

// ---- CNN body ----
__device__ __forceinline__ void cnn_body(
    int g, char* smem,
    const float* __restrict__ xo,
    const float* __restrict__ w1, const float* __restrict__ b1,
    const u16t* __restrict__ W2k, const float* __restrict__ b2,
    const u16t* __restrict__ W3k, const float* __restrict__ b3,
    u16t* __restrict__ t3)
{
  float* xot = (float*)(smem);
  float* w1s = (float*)(smem + 3072);
  float* b2s = (float*)(smem + 4096);
  float* b3s = (float*)(smem + 4352);
  short* T1T = (short*)(smem + 4864);
  char*  T2B = smem + 20736;
  u16t*  stg = (u16t*)(smem + 4864);

  const int t = threadIdx.x;
  const int w = t >> 6, l = t & 63, col = l & 15, kg = l >> 4;

  for (int i = t; i < 768; i += 256) xot[i] = (i < 735) ? xo[(size_t)g * 735 + i] : 0.f;
  w1s[t] = w1[t];
  if (t < 64) b2s[t] = b2[t];
  if (t < 128) b3s[t] = b3[t];
  if (t < 192) {
    int r = 242 + (t >> 5), c = t & 31;
    T1T[r * 32 + c] = 0;
  }
  __syncthreads();

  {
    const int c = t >> 3, qg = t & 7;
    float wv[8];
#pragma unroll
    for (int j = 0; j < 8; ++j) wv[j] = w1s[c * 8 + j];
    const float bias = b1[c];
    const int q0 = qg * 31, qe = (q0 + 31 < 242) ? q0 + 31 : 242;
#pragma unroll 1
    for (int qc = q0; qc < qe; qc += 10) {
      const int cnt = (qe - qc < 10) ? qe - qc : 10;
      float xv[37];
#pragma unroll
      for (int j = 0; j < 37; ++j) xv[j] = xot[3 * qc + j];
#pragma unroll
      for (int j0 = 0; j0 < 10; ++j0) {
        if (j0 < cnt) {
          float a0 = bias, a1 = bias, a2 = bias;
#pragma unroll
          for (int tt = 0; tt < 8; ++tt) {
            a0 = fmaf(wv[tt], xv[3 * j0 + tt], a0);
            a1 = fmaf(wv[tt], xv[3 * j0 + 1 + tt], a1);
            a2 = fmaf(wv[tt], xv[3 * j0 + 2 + tt], a2);
          }
          float m = fmaxf(fmaxf(a0, a1), fmaxf(a2, 0.f));
          const int pos = qc + j0;
          T1T[pos * 32 + (c ^ ((pos & 3) << 3))] = (short)f2bf(m);
        }
      }
    }
  }
  __syncthreads();

  {
    bf16x8 am[8];
#pragma unroll
    for (int kk = 0; kk < 8; ++kk)
      am[kk] = *(const bf16x8*)(W2k + (w * 16 + col) * 256 + kk * 32 + kg * 8);
#pragma unroll 1
    for (int qt = 0; qt < 5; ++qt) {
      const int rbase = qt * 48 + col * 3;
      bf16x8 rv[10];
#pragma unroll
      for (int s = 0; s < 10; ++s) {
        const int row = rbase + s;
        rv[s] = *(const bf16x8*)(T1T + row * 32 + ((kg ^ (row & 3)) << 3));
      }
      f32x4 a0 = {0.f, 0.f, 0.f, 0.f}, a1 = a0, a2 = a0;
#pragma unroll
      for (int kk = 0; kk < 8; ++kk) {
        a0 = __builtin_amdgcn_mfma_f32_16x16x32_bf16(am[kk], rv[kk], a0, 0, 0, 0);
        a1 = __builtin_amdgcn_mfma_f32_16x16x32_bf16(am[kk], rv[kk + 1], a1, 0, 0, 0);
        a2 = __builtin_amdgcn_mfma_f32_16x16x32_bf16(am[kk], rv[kk + 2], a2, 0, 0, 0);
      }
      const int q = qt * 16 + col;
      if (q < 78) {
        union { u16t u[4]; uint2 v; } pk;
#pragma unroll
        for (int r = 0; r < 4; ++r) {
          const float bb = b2s[w * 16 + kg * 4 + r];
          float m = fmaxf(fmaxf(a0[r], a1[r]), a2[r]);
          pk.u[r] = f2bf(fmaxf(m + bb, 0.f));
        }
        const int boff = (q * 128 + (w * 16 + kg * 4) * 2) ^ ((q & 7) << 4);
        *(uint2*)(T2B + boff) = pk.v;
      }
    }
  }
  __syncthreads();

  {
#pragma unroll 1
    for (int mi = 0; mi < 2; ++mi) {
      const int m3 = w * 2 + mi;
      f32x4 acc[2][3];
#pragma unroll
      for (int qt = 0; qt < 2; ++qt)
#pragma unroll
        for (int r = 0; r < 3; ++r) acc[qt][r] = (f32x4){0.f, 0.f, 0.f, 0.f};
#pragma unroll 1
      for (int kh = 0; kh < 2; ++kh) {
        bf16x8 amh[8];
#pragma unroll
        for (int tt = 0; tt < 8; ++tt)
          amh[tt] = *(const bf16x8*)(W3k + (m3 * 16 + col) * 512 + (tt * 2 + kh) * 32 + kg * 8);
#pragma unroll
        for (int qt = 0; qt < 2; ++qt) {
          const int rbase = qt * 48 + col * 3;
          bf16x8 rv[10];
#pragma unroll
          for (int s = 0; s < 10; ++s) {
            int row = rbase + s;
            row = (row < 78) ? row : 77;
            const int boff = (row * 128 + kh * 64 + kg * 16) ^ ((row & 7) << 4);
            rv[s] = *(const bf16x8*)(T2B + boff);
          }
#pragma unroll
          for (int tt = 0; tt < 8; ++tt) {
            acc[qt][0] = __builtin_amdgcn_mfma_f32_16x16x32_bf16(amh[tt], rv[tt], acc[qt][0], 0, 0, 0);
            acc[qt][1] = __builtin_amdgcn_mfma_f32_16x16x32_bf16(amh[tt], rv[tt + 1], acc[qt][1], 0, 0, 0);
            acc[qt][2] = __builtin_amdgcn_mfma_f32_16x16x32_bf16(amh[tt], rv[tt + 2], acc[qt][2], 0, 0, 0);
          }
        }
      }
#pragma unroll
      for (int qt = 0; qt < 2; ++qt) {
        const int q = qt * 16 + col;
        if (q < 23) {
#pragma unroll
          for (int r = 0; r < 4; ++r) {
            const int c = m3 * 16 + kg * 4 + r;
            float m = fmaxf(fmaxf(acc[qt][0][r], acc[qt][1][r]), acc[qt][2][r]);
            stg[c * 23 + q] = f2bf(fmaxf(m + b3s[c], 0.f));
          }
        }
      }
    }
  }
  __syncthreads();

  {
    const uint4* s4 = (const uint4*)stg;
    uint4* d4 = (uint4*)(t3 + (size_t)g * 2944);
    for (int id = t; id < 368; id += 256) d4[id] = s4[id];
  }
}

// ---- fused launch: 5 layer blocks + 2 cnn blocks per group of 7; 5 blocks/CU ----
__global__ __launch_bounds__(256, 5) void k_fused(
    const u16t* __restrict__ yin, const u32t* __restrict__ rs, const int* __restrict__ ssrc,
    const float* __restrict__ stats, const float* __restrict__ gamma, const float* __restrict__ beta,
    const float* __restrict__ W1, const float* __restrict__ b1,
    const float* __restrict__ W2, const float* __restrict__ b2,
    u16t* __restrict__ yout, float* __restrict__ stats_out,
    const float* __restrict__ xo, const float* __restrict__ c1W, const float* __restrict__ c1b,
    const u16t* __restrict__ W2k, const float* __restrict__ c2b,
    const u16t* __restrict__ W3k, const float* __restrict__ c3b,
    u16t* __restrict__ t3, int cnn_g0)
{
  __shared__ __align__(16) char smem[30720];
  const int grp = blockIdx.x / 7, rem = blockIdx.x % 7;
  if (rem < 5)
    layer_body(grp * 5 + rem, smem, yin, rs, ssrc, stats, gamma, beta,
               W1, b1, W2, b2, yout, stats_out);
  else
    cnn_body(cnn_g0 + grp * 2 + (rem - 5), smem, xo, c1W, c1b, W2k, c2b, W3k, c3b, t3);
}

__global__ __launch_bounds__(64) void k_pool_xd(
    const u16t* __restrict__ y, const int* __restrict__ batch,
    const float* __restrict__ stats, const float* __restrict__ gamma,
    const float* __restrict__ beta, const float* __restrict__ Wxd,
    const float* __restrict__ bxd, u16t* __restrict__ xc)
{
  const int g = blockIdx.x, t = threadIdx.x;
  int lo = 0, n = NN;
  while (n > 0) {
    int h = n >> 1, m = lo + h;
    if (batch[m] < g) { lo = m + 1; n -= h + 1; } else n = h;
  }
  int hi = lo;
  n = NN - lo;
  while (n > 0) {
    int h = n >> 1, m = hi + h;
    if (batch[m] < g + 1) { hi = m + 1; n -= h + 1; } else n = h;
  }
  const int c = t & 31;
  const float mu = stats[4 * 64 + c] * (1.f / NN);
  float var = fmaxf(stats[4 * 64 + 32 + c] * (1.f / NN) - mu * mu, 0.f);
  const float sc = gamma[4 * 32 + c] * rsqrtf(var + BN_EPS);
  const float sh = beta[4 * 32 + c] - mu * sc;
  float acc = 0.f;
  for (int i = lo + (t >> 5); i < hi; i += 2) acc += h2f(y[(size_t)i * 32 + c]);
  acc += __shfl_down(acc, 32);
  __shared__ float pl[32];
  if (t < 32) pl[t] = acc * sc + (float)(hi - lo) * sh;
  __syncthreads();
#pragma unroll
  for (int rep = 0; rep < 2; ++rep) {
    const int o = t + rep * 64;
    float a = bxd[o];
#pragma unroll
    for (int cc = 0; cc < 32; ++cc) a = fmaf(pl[cc], Wxd[cc * 128 + o], a);
    xc[(size_t)g * 256 + o] = f2bf(fmaxf(a, 0.f));
  }
}

// ---------------- weight prep ----------------
__global__ __launch_bounds__(256) void k_prep(
    const float* __restrict__ w2, const float* __restrict__ w3,
    const float* __restrict__ wxt, const float* __restrict__ wf1, const float* __restrict__ wf2,
    u16t* __restrict__ W2k, u16t* __restrict__ W3k,
    u16t* __restrict__ WXT, u16t* __restrict__ WF1, u16t* __restrict__ WF2)
{
  const int i = blockIdx.x * 256 + threadIdx.x;
  if (i < 64 * 256) {
    int c2 = i >> 8, kk = i & 255, tt = kk >> 5, ci = kk & 31;
    W2k[i] = f2bf(w2[c2 * 256 + ci * 8 + tt]);
  }
  if (i < 128 * 512) {
    int c3 = i >> 9, kk = i & 511, tt = kk >> 6, ci = kk & 63;
    W3k[i] = f2bf(w3[c3 * 512 + ci * 8 + tt]);
  }
  if (i < 128 * 2944) {
    int nn = i / 2944, kk = i - nn * 2944;
    WXT[i] = f2bf(wxt[kk * 128 + nn]);
  }
  if (i < 1024 * 256) {
    int nn = i >> 8, kk = i & 255;
    WF1[i] = f2bf(wf1[kk * 1024 + nn]);
  }
  if (i < 128 * 1024) {
    int nn = i >> 10, kk = i & 1023;
    WF2[i] = f2bf(wf2[kk * 128 + nn]);
  }
}

// ---------------- bf16 MFMA GEMM ----------------
__global__ __launch_bounds__(256) void k_mgemm(
    const u16t* __restrict__ A, int lda,
    const u16t* __restrict__ WT, const float* __restrict__ bias,
    void* __restrict__ Cv, int ldc, int c_off, int M, int Kd,
    int relu_f, int out32)
{
  __shared__ __align__(16) u16t As[128 * 4 * 8];
  __shared__ __align__(16) u16t Ws2[64 * 4 * 8];
  const int t = threadIdx.x;
  const int w = t >> 6, l = t & 63, col = l & 15, kg = l >> 4;
  const int wm = w & 1, wn = w >> 1;
  const int m0 = blockIdx.x * 128, n0 = blockIdx.y * 64;
  f32x4 acc[4][2];
#pragma unroll
  for (int i = 0; i < 4; ++i)
#pragma unroll
    for (int j = 0; j < 2; ++j) acc[i][j] = (f32x4){0.f, 0.f, 0.f, 0.f};
  const int ar = t >> 1, ac = (t & 1) * 2;
  const int wr = t >> 2, wc = t & 3;
  const bool aok = (m0 + ar) < M;
  const u16t* Ap = A + (size_t)(m0 + ar) * lda;
  const u16t* Wp = WT + (size_t)(n0 + wr) * Kd;
  for (int k0 = 0; k0 < Kd; k0 += 32) {
    bf16x8 av0 = {0, 0, 0, 0, 0, 0, 0, 0}, av1 = {0, 0, 0, 0, 0, 0, 0, 0};
    if (aok) {
      av0 = *(const bf16x8*)(Ap + k0 + ac * 8);
      av1 = *(const bf16x8*)(Ap + k0 + (ac + 1) * 8);
    }
    const bf16x8 wv = *(const bf16x8*)(Wp + k0 + wc * 8);
    __syncthreads();
    *(bf16x8*)(As + (ar * 4 + (ac ^ (ar & 3))) * 8) = av0;
    *(bf16x8*)(As + (ar * 4 + ((ac + 1) ^ (ar & 3))) * 8) = av1;
    *(bf16x8*)(Ws2 + (wr * 4 + (wc ^ (wr & 3))) * 8) = wv;
    __syncthreads();
    bf16x8 af[4], bf[2];
#pragma unroll
    for (int i = 0; i < 4; ++i) {
      const int R = wm * 64 + i * 16 + col;
      af[i] = *(const bf16x8*)(As + (R * 4 + (kg ^ (R & 3))) * 8);
    }
#pragma unroll
    for (int j = 0; j < 2; ++j) {
      const int R = wn * 32 + j * 16 + col;
      bf[j] = *(const bf16x8*)(Ws2 + (R * 4 + (kg ^ (R & 3))) * 8);
    }
#pragma unroll
    for (int i = 0; i < 4; ++i)
#pragma unroll
      for (int j = 0; j < 2; ++j)
        acc[i][j] = __builtin_amdgcn_mfma_f32_16x16x32_bf16(af[i], bf[j], acc[i][j], 0, 0, 0);
  }
#pragma unroll
  for (int j = 0; j < 2; ++j) {
    const int gn = n0 + wn * 32 + j * 16 + col;
    const float bb = bias[gn];
#pragma unroll
    for (int i = 0; i < 4; ++i) {
      const int gmb = m0 + wm * 64 + i * 16 + kg * 4;
#pragma unroll
      for (int r = 0; r < 4; ++r) {
        const int gm = gmb + r;
        if (gm < M) {
          float v = acc[i][j][r] + bb;
          if (relu_f) v = fmaxf(v, 0.f);
          if (out32) ((float*)Cv)[(size_t)gm * ldc + c_off + gn] = v;
          else ((u16t*)Cv)[(size_t)gm * ldc + c_off + gn] = f2bf(v);
        }
      }
    }
  }
}

__global__ __launch_bounds__(256) void k_out(
    const float* __restrict__ h2, const float* __restrict__ Wo,
    const float* __restrict__ bo, float* __restrict__ out)
{
  __shared__ float Ws_[128];
  const int t = threadIdx.x;
  if (t < 128) Ws_[t] = Wo[t];
  __syncthreads();
  const int g = blockIdx.x * 32 + (t >> 3), l = t & 7;
  float acc = 0.f;
  if (g < NG) {
    const float* hr = h2 + (size_t)g * 128 + l * 16;
    const float* wr = Ws_ + l * 16;
#pragma unroll
    for (int j = 0; j < 16; ++j) acc = fmaf(hr[j], wr[j], acc);
  }
  acc += __shfl_down(acc, 4, 8);
  acc += __shfl_down(acc, 2, 8);
  acc += __shfl_down(acc, 1, 8);
  if (l == 0 && g < NG) out[g] = acc + bo[0];
}

extern "C" void kernel_launch(void* const* d_in, const int* in_sizes, int n_in,
                              void* d_out, int out_size, void* d_ws, size_t ws_size,
                              hipStream_t stream) {
  const float* x    = (const float*)d_in[0];
  const int*   ei   = (const int*)d_in[1];
  const int*   batch= (const int*)d_in[2];
  const float* xo   = (const float*)d_in[3];
  const float* g1W1 = (const float*)d_in[4];
  const float* g1b1 = (const float*)d_in[5];
  const float* g1W2 = (const float*)d_in[6];
  const float* g1b2 = (const float*)d_in[7];
  const float* gsW1 = (const float*)d_in[8];
  const float* gsb1 = (const float*)d_in[9];
  const float* gsW2 = (const float*)d_in[10];
  const float* gsb2 = (const float*)d_in[11];
  const float* bng  = (const float*)d_in[12];
  const float* bnb  = (const float*)d_in[13];
  const float* Wxd  = (const float*)d_in[14];
  const float* bxd  = (const float*)d_in[15];
  const float* c1W  = (const float*)d_in[16];
  const float* c1b  = (const float*)d_in[17];
  const float* c2W  = (const float*)d_in[18];
  const float* c2b  = (const float*)d_in[19];
  const float* c3W  = (const float*)d_in[20];
  const float* c3b  = (const float*)d_in[21];
  const float* Wxt  = (const float*)d_in[22];
  const float* bxt  = (const float*)d_in[23];
  const float* W1f  = (const float*)d_in[24];
  const float* b1f  = (const float*)d_in[25];
  const float* W2f  = (const float*)d_in[26];
  const float* b2f  = (const float*)d_in[27];
  const float* Wo   = (const float*)d_in[28];
  const float* bo   = (const float*)d_in[29];

  char* ws = (char*)d_ws;
  u16t*  U    = (u16t*)(ws + OFF_U);
  u16t*  YA   = (u16t*)(ws + OFF_YA);
  u16t*  YB   = (u16t*)(ws + OFF_YB);
  float* ST   = (float*)(ws + OFF_ST);
  u32t*  RS   = (u32t*)(ws + OFF_RS);
  u32t*  CUR  = (u32t*)(ws + OFF_CUR);
  u32t*  BS   = (u32t*)(ws + OFF_BSUM);
  int*   SSRC = (int*)(ws + OFF_SSRC);
  u16t*  WK   = (u16t*)(ws + OFF_WK);
  u16t*  W2K  = WK;
  u16t*  W3K  = WK + 16384;
  u16t*  WXT  = WK + 16384 + 65536;
  u16t*  WF1  = WK + 16384 + 65536 + 376832;
  u16t*  WF2  = WK + 16384 + 65536 + 376832 + 262144;
  u16t*  XC   = (u16t*)(ws + OFF_XC);
  u16t*  T3   = (u16t*)(ws + OFF_T3);
  u16t*  H1   = (u16t*)(ws + OFF_H1);
  float* H2   = (float*)(ws + OFF_H2);
  float* OUT  = (float*)d_out;

  const int NBLK = (NN + 1023) / 1024;

  hipMemsetAsync(ST, 0, 5 * 64 * sizeof(float), stream);
  hipMemsetAsync(CUR, 0, NN * sizeof(u32t), stream);

  k_prep<<<(128 * 2944 + 255) / 256, 256, 0, stream>>>(c2W, c3W, Wxt, W1f, W2f,
                                                        W2K, W3K, WXT, WF1, WF2);

  k_hist<<<(NE + 255) / 256, 256, 0, stream>>>(ei, CUR);
  k_scan1<<<NBLK, 256, 0, stream>>>(CUR, BS);
  k_scan2<<<1, 256, 0, stream>>>(BS, RS, NBLK);
  k_scan3<<<NBLK, 256, 0, stream>>>(CUR, RS, BS);
  for (int p = 0; p < 4; ++p)
    k_scatter<<<(NE + 255) / 256, 256, 0, stream>>>(ei, CUR, SSRC, p);

  k_mlp1_first<<<NN / 64, 256, 0, stream>>>(x, g1W1, U);
  k_agg0<<<NN / 64, 256, 0, stream>>>(U, RS, SSRC, g1b1, g1W2, g1b2, YA, ST + 0);

  const u16t* yin = YA;
  u16t* yout = YB;
  for (int lyr = 1; lyr <= 4; ++lyr) {
    k_fused<<<21875, 256, 0, stream>>>(yin, RS, SSRC, ST + (lyr - 1) * 64,
                                       bng + (lyr - 1) * 32, bnb + (lyr - 1) * 32,
                                       gsW1 + (lyr - 1) * 1024, gsb1 + (lyr - 1) * 32,
                                       gsW2 + (lyr - 1) * 1024, gsb2 + (lyr - 1) * 32,
                                       yout, ST + lyr * 64,
                                       xo, c1W, c1b, W2K, c2b, W3K, c3b, T3,
                                       (lyr - 1) * 6250);
    const u16t* tmp = yin;
    yin = yout;
    yout = (u16t*)tmp;
  }
  k_pool_xd<<<NG, 64, 0, stream>>>(yin, batch, ST, bng, bnb, Wxd, bxd, XC);

  {
    dim3 grid((NG + 127) / 128, 2);
    k_mgemm<<<grid, 256, 0, stream>>>(T3, 2944, WXT, bxt, XC, 256, 128, NG, 2944, 0, 0);
  }
  {
    dim3 grid((NG + 127) / 128, 16);
    k_mgemm<<<grid, 256, 0, stream>>>(XC, 256, WF1, b1f, H1, 1024, 0, NG, 256, 1, 0);
  }
  {
    dim3 grid((NG + 127) / 128, 2);
    k_mgemm<<<grid, 256, 0, stream>>>(H1, 1024, WF2, b2f, H2, 128, 0, NG, 1024, 1, 1);
  }
  k_out<<<(NG + 31) / 32, 256, 0, stream>>>(H2, Wo, bo, OUT);
}

// Round 18
// 2014.453 us; speedup vs baseline: 1.0743x; 1.0743x over previous
//
#include <hip/hip_runtime.h>

#define NN 1000000
#define NE 4000000
#define NG 25000
#define BN_EPS 1e-5f

typedef unsigned short u16t;
typedef unsigned int u32t;
typedef __attribute__((ext_vector_type(8))) short bf16x8;
typedef __attribute__((ext_vector_type(8))) _Float16 f16x8;
typedef __attribute__((ext_vector_type(4))) float f32x4;

__device__ inline u16t f2bf(float f) {
  u32t u = __float_as_uint(f);
  u32t r = (u + 0x7FFFu + ((u >> 16) & 1u)) >> 16;
  return (u16t)r;
}
__device__ inline float bf2f(u16t h) { return __uint_as_float((u32t)h << 16); }
__device__ inline u16t f2h(float f) {
  _Float16 h = (_Float16)f;
  return *(u16t*)&h;
}
__device__ inline float h2f(u16t v) {
  _Float16 h = *(_Float16*)&v;
  return (float)h;
}
__device__ inline void add8h(float* a, uint4 v) {
  union { uint4 u; _Float16 h[8]; } cv;
  cv.u = v;
#pragma unroll
  for (int j = 0; j < 8; ++j) a[j] += (float)cv.h[j];
}

// ---- workspace layout (bytes) ----
static const size_t OFF_U    = 0;
static const size_t OFF_T3   = 0;
static const size_t OFF_YA   = 150000000;
static const size_t OFF_YB   = 214000000;
static const size_t OFF_ST   = 278000000;
static const size_t OFF_RS   = 279000000;
static const size_t OFF_CUR  = 283200000;
static const size_t OFF_BSUM = 287300000;
static const size_t OFF_SSRC = 288000000;
static const size_t OFF_WK   = 304000000;
static const size_t OFF_XC   = 306000000;
static const size_t OFF_H1   = 150000000;
static const size_t OFF_H2   = 214000000;

// ---------------- CSR build ----------------
__global__ __launch_bounds__(256) void k_hist(const int* __restrict__ ei, u32t* __restrict__ cnt) {
  const int i = blockIdx.x * 256 + threadIdx.x;
  if (i < NE) atomicAdd(&cnt[ei[NE + i]], 1u);
}

__global__ __launch_bounds__(256) void k_scan1(const u32t* __restrict__ deg, u32t* __restrict__ bsum) {
  __shared__ u32t red[4];
  const int b = blockIdx.x, t = threadIdx.x;
  u32t s = 0;
#pragma unroll
  for (int j = 0; j < 4; ++j) {
    const int i = b * 1024 + j * 256 + t;
    if (i < NN) s += deg[i];
  }
#pragma unroll
  for (int off = 32; off > 0; off >>= 1) s += __shfl_down(s, off);
  if ((t & 63) == 0) red[t >> 6] = s;
  __syncthreads();
  if (t == 0) bsum[b] = red[0] + red[1] + red[2] + red[3];
}

__global__ __launch_bounds__(256) void k_scan2(u32t* __restrict__ bsum, u32t* __restrict__ rs, int nblk) {
  __shared__ u32t sh[256];
  const int t = threadIdx.x;
  u32t v[4];
#pragma unroll
  for (int j = 0; j < 4; ++j) {
    const int i = t * 4 + j;
    v[j] = (i < nblk) ? bsum[i] : 0u;
  }
  const u32t tot = v[0] + v[1] + v[2] + v[3];
  sh[t] = tot;
  __syncthreads();
  for (int off = 1; off < 256; off <<= 1) {
    u32t add = (t >= off) ? sh[t - off] : 0u;
    __syncthreads();
    sh[t] += add;
    __syncthreads();
  }
  const u32t tb = (t == 0) ? 0u : sh[t - 1];
  u32t run = tb;
#pragma unroll
  for (int j = 0; j < 4; ++j) {
    const int i = t * 4 + j;
    if (i < nblk) bsum[i] = run;
    run += v[j];
  }
  if (t == 0) rs[NN] = NE;
}

__global__ __launch_bounds__(256) void k_scan3(u32t* __restrict__ cur, u32t* __restrict__ rs,
                                               const u32t* __restrict__ bsum) {
  __shared__ u32t sh[256];
  const int b = blockIdx.x, t = threadIdx.x;
  const int i0 = b * 1024 + t * 4;
  u32t v[4];
#pragma unroll
  for (int j = 0; j < 4; ++j) v[j] = (i0 + j < NN) ? cur[i0 + j] : 0u;
  sh[t] = v[0] + v[1] + v[2] + v[3];
  __syncthreads();
  for (int off = 1; off < 256; off <<= 1) {
    u32t add = (t >= off) ? sh[t - off] : 0u;
    __syncthreads();
    sh[t] += add;
    __syncthreads();
  }
  u32t run = bsum[b] + ((t == 0) ? 0u : sh[t - 1]);
#pragma unroll
  for (int j = 0; j < 4; ++j) {
    const int i = i0 + j;
    if (i < NN) { rs[i] = run; cur[i] = run; }
    run += v[j];
  }
}

// dst-range-partitioned scatter: pass p handles dst>>18 == p (4 passes).
__global__ __launch_bounds__(256) void k_scatter(const int* __restrict__ ei,
                                                 u32t* __restrict__ cur, int* __restrict__ ssrc,
                                                 int pass) {
  const int i = blockIdx.x * 256 + threadIdx.x;
  if (i < NE) {
    const int dst = ei[NE + i];
    if ((dst >> 18) == pass) {
      const int src = ei[i];
      const u32t pos = atomicAdd(&cur[dst], 1u);
      ssrc[pos] = src;
    }
  }
}

// ---------------- GNN kernels ----------------

__global__ __launch_bounds__(256) void k_mlp1_first(
    const float* __restrict__ x, const float* __restrict__ W1, u16t* __restrict__ u)
{
  __shared__ __align__(16) u16t Xh[64 * 104];
  __shared__ __align__(16) u16t Wt[32 * 104];
  __shared__ __align__(16) u16t Uh[64 * 40];
  const int t = threadIdx.x;
  const int n0b = blockIdx.x * 64;
  for (int id = t; id < 64 * 78; id += 256) {
    const int row = id / 78, k = id - row * 78;
    Xh[row * 104 + k] = f2h(x[(size_t)n0b * 78 + id]);
  }
  for (int id = t; id < 64 * 18; id += 256) {
    const int row = id / 18, k = 78 + (id - row * 18);
    Xh[row * 104 + k] = 0;
  }
  for (int id = t; id < 78 * 32; id += 256) {
    const int k = id >> 5, c = id & 31;
    Wt[c * 104 + k] = f2h(W1[id]);
  }
  for (int id = t; id < 32 * 18; id += 256) {
    const int c = id / 18, k = 78 + (id - c * 18);
    Wt[c * 104 + k] = 0;
  }
  __syncthreads();
  {
    const int w = t >> 6, l = t & 63, col = l & 15, kg = l >> 4;
    const int m0 = w * 16;
    f32x4 ac0 = {0.f, 0.f, 0.f, 0.f}, ac1 = {0.f, 0.f, 0.f, 0.f};
#pragma unroll
    for (int ks = 0; ks < 3; ++ks) {
      const f16x8 af = *(const f16x8*)(Xh + (m0 + col) * 104 + ks * 32 + kg * 8);
      const f16x8 bf0 = *(const f16x8*)(Wt + col * 104 + ks * 32 + kg * 8);
      const f16x8 bf1 = *(const f16x8*)(Wt + (16 + col) * 104 + ks * 32 + kg * 8);
      ac0 = __builtin_amdgcn_mfma_f32_16x16x32_f16(af, bf0, ac0, 0, 0, 0);
      ac1 = __builtin_amdgcn_mfma_f32_16x16x32_f16(af, bf1, ac1, 0, 0, 0);
    }
#pragma unroll
    for (int r = 0; r < 4; ++r) {
      const int m = m0 + kg * 4 + r;
      Uh[m * 40 + col] = f2h(ac0[r]);
      Uh[m * 40 + 16 + col] = f2h(ac1[r]);
    }
  }
  __syncthreads();
  {
    const int row = t >> 2;
    const uint4 v = *(const uint4*)(Uh + row * 40 + (t & 3) * 8);
    *(uint4*)(u + (size_t)(n0b + row) * 32 + (t & 3) * 8) = v;
  }
}

__global__ __launch_bounds__(256) void k_agg0(
    const u16t* __restrict__ u, const u32t* __restrict__ rs, const int* __restrict__ ssrc,
    const float* __restrict__ b1, const float* __restrict__ W2, const float* __restrict__ b2,
    u16t* __restrict__ yout, float* __restrict__ stats_out)
{
  __shared__ __align__(16) u16t W2t[32 * 40];
  __shared__ __align__(16) u16t A1h[64 * 40];
  __shared__ __align__(16) u16t A2h[64 * 40];
  __shared__ float red[256];
  __shared__ u32t rss[65];
  const int t = threadIdx.x;
  const int n0b = blockIdx.x * 64;
  for (int id = t; id < 1024; id += 256) {
    int k = id >> 5, c = id & 31;
    W2t[c * 40 + k] = f2h(W2[id]);
  }
  if (t < 65) rss[t] = rs[n0b + t];
  __syncthreads();
  const int nl = t >> 2, c0 = (t & 3) * 8;
  {
    const int n = n0b + nl;
    float a[8] = {};
    add8h(a, *(const uint4*)(u + (size_t)n * 32 + c0));
    const u32t e0 = rss[nl], e1 = rss[nl + 1];
    u32t e = e0;
    for (; e + 4 <= e1; e += 4) {
      const int s0v = ssrc[e], s1v = ssrc[e + 1], s2v = ssrc[e + 2], s3v = ssrc[e + 3];
      const uint4 v0 = *(const uint4*)(u + (size_t)s0v * 32 + c0);
      const uint4 v1 = *(const uint4*)(u + (size_t)s1v * 32 + c0);
      const uint4 v2 = *(const uint4*)(u + (size_t)s2v * 32 + c0);
      const uint4 v3 = *(const uint4*)(u + (size_t)s3v * 32 + c0);
      add8h(a, v0); add8h(a, v1); add8h(a, v2); add8h(a, v3);
    }
    for (; e < e1; ++e)
      add8h(a, *(const uint4*)(u + (size_t)ssrc[e] * 32 + c0));
    union { u16t h[8]; uint4 v; } pk;
#pragma unroll
    for (int j = 0; j < 8; ++j) pk.h[j] = f2h(fmaxf(a[j] + b1[c0 + j], 0.f));
    *(uint4*)(A1h + nl * 40 + c0) = pk.v;
  }
  __syncthreads();
  {
    const int w = t >> 6, l = t & 63, col = l & 15, kg = l >> 4;
    const int m0 = w * 16;
    const f16x8 af = *(const f16x8*)(A1h + (m0 + col) * 40 + kg * 8);
    const f16x8 bf0 = *(const f16x8*)(W2t + col * 40 + kg * 8);
    const f16x8 bf1 = *(const f16x8*)(W2t + (16 + col) * 40 + kg * 8);
    f32x4 ac0 = {0.f, 0.f, 0.f, 0.f}, ac1 = {0.f, 0.f, 0.f, 0.f};
    ac0 = __builtin_amdgcn_mfma_f32_16x16x32_f16(af, bf0, ac0, 0, 0, 0);
    ac1 = __builtin_amdgcn_mfma_f32_16x16x32_f16(af, bf1, ac1, 0, 0, 0);
    const float bb0 = b2[col], bb1 = b2[16 + col];
#pragma unroll
    for (int r = 0; r < 4; ++r) {
      const int m = m0 + kg * 4 + r;
      A2h[m * 40 + col] = f2h(fmaxf(ac0[r] + bb0, 0.f));
      A2h[m * 40 + 16 + col] = f2h(fmaxf(ac1[r] + bb1, 0.f));
    }
  }
  __syncthreads();
  const int c = t & 31;
  float rsum = 0.f, rq = 0.f;
#pragma unroll
  for (int rep = 0; rep < 8; ++rep) {
    const int row = (t >> 5) + rep * 8;
    const float v = h2f(A2h[row * 40 + c]);
    rsum += v;
    rq += v * v;
  }
  {
    const int row = t >> 2;
    const uint4 v = *(const uint4*)(A2h + row * 40 + (t & 3) * 8);
    *(uint4*)(yout + (size_t)(n0b + row) * 32 + (t & 3) * 8) = v;
  }
  rsum += __shfl_down(rsum, 32);
  rq += __shfl_down(rq, 32);
  __syncthreads();
  const int wv_ = t >> 6, lane = t & 63;
  if (lane < 32) {
    red[wv_ * 32 + lane] = rsum;
    red[128 + wv_ * 32 + lane] = rq;
  }
  __syncthreads();
  if (t < 32) {
    float aa = red[t] + red[32 + t] + red[64 + t] + red[96 + t];
    float bb = red[128 + t] + red[160 + t] + red[192 + t] + red[224 + t];
    unsafeAtomicAdd(&stats_out[t], aa);
    unsafeAtomicAdd(&stats_out[32 + t], bb);
  }
}

// ---- layer body (layers 1..4) ----
__device__ __forceinline__ void layer_body(
    int bid, char* smem,
    const u16t* __restrict__ yin, const u32t* __restrict__ rs, const int* __restrict__ ssrc,
    const float* __restrict__ stats, const float* __restrict__ gamma, const float* __restrict__ beta,
    const float* __restrict__ W1, const float* __restrict__ b1,
    const float* __restrict__ W2, const float* __restrict__ b2,
    u16t* __restrict__ yout, float* __restrict__ stats_out)
{
  u16t* W1t = (u16t*)smem;
  u16t* W2t = (u16t*)(smem + 2560);
  u16t* A1h = (u16t*)(smem + 5120);
  u16t* A2h = (u16t*)(smem + 10240);
  float* red = (float*)(smem + 15360);
  u32t* rss = (u32t*)(smem + 16384);
  const int t = threadIdx.x;
  const int n0b = bid * 64;
  for (int id = t; id < 1024; id += 256) {
    int k = id >> 5, c = id & 31;
    W1t[c * 40 + k] = f2h(W1[id]);
    W2t[c * 40 + k] = f2h(W2[id]);
  }
  if (t < 65) rss[t] = rs[n0b + t];
  __syncthreads();
  const int nl = t >> 2, c0 = (t & 3) * 8;
  {
    const int n = n0b + nl;
    float sc[8], sh[8];
#pragma unroll
    for (int j = 0; j < 8; ++j) {
      const int c = c0 + j;
      const float mu = stats[c] * (1.f / NN);
      float var = fmaxf(stats[32 + c] * (1.f / NN) - mu * mu, 0.f);
      sc[j] = gamma[c] * rsqrtf(var + BN_EPS);
      sh[j] = beta[c] - mu * sc[j];
    }
    float a[8] = {};
    add8h(a, *(const uint4*)(yin + (size_t)n * 32 + c0));
    const u32t e0 = rss[nl], e1 = rss[nl + 1];
    u32t e = e0;
    for (; e + 4 <= e1; e += 4) {
      const int s0v = ssrc[e], s1v = ssrc[e + 1], s2v = ssrc[e + 2], s3v = ssrc[e + 3];
      const uint4 v0 = *(const uint4*)(yin + (size_t)s0v * 32 + c0);
      const uint4 v1 = *(const uint4*)(yin + (size_t)s1v * 32 + c0);
      const uint4 v2 = *(const uint4*)(yin + (size_t)s2v * 32 + c0);
      const uint4 v3 = *(const uint4*)(yin + (size_t)s3v * 32 + c0);
      add8h(a, v0); add8h(a, v1); add8h(a, v2); add8h(a, v3);
    }
    for (; e < e1; ++e)
      add8h(a, *(const uint4*)(yin + (size_t)ssrc[e] * 32 + c0));
    const float cnt = (float)(e1 - e0 + 1u);
    union { u16t h[8]; uint4 v; } pk;
#pragma unroll
    for (int j = 0; j < 8; ++j) pk.h[j] = f2h(sc[j] * a[j] + cnt * sh[j]);
    *(uint4*)(A1h + nl * 40 + c0) = pk.v;
  }
  __syncthreads();
  const int w = t >> 6, l = t & 63, col = l & 15, kg = l >> 4;
  const int m0 = w * 16;
  {
    const f16x8 af = *(const f16x8*)(A1h + (m0 + col) * 40 + kg * 8);
    const f16x8 bf0 = *(const f16x8*)(W1t + col * 40 + kg * 8);
    const f16x8 bf1 = *(const f16x8*)(W1t + (16 + col) * 40 + kg * 8);
    f32x4 ac0 = {0.f, 0.f, 0.f, 0.f}, ac1 = {0.f, 0.f, 0.f, 0.f};
    ac0 = __builtin_amdgcn_mfma_f32_16x16x32_f16(af, bf0, ac0, 0, 0, 0);
    ac1 = __builtin_amdgcn_mfma_f32_16x16x32_f16(af, bf1, ac1, 0, 0, 0);
    const float bb0 = b1[col], bb1 = b1[16 + col];
#pragma unroll
    for (int r = 0; r < 4; ++r) {
      const int m = m0 + kg * 4 + r;
      A2h[m * 40 + col] = f2h(fmaxf(ac0[r] + bb0, 0.f));
      A2h[m * 40 + 16 + col] = f2h(fmaxf(ac1[r] + bb1, 0.f));
    }
  }
  __syncthreads();
  {
    const f16x8 af = *(const f16x8*)(A2h + (m0 + col) * 40 + kg * 8);
    const f16x8 bf0 = *(const f16x8*)(W2t + col * 40 + kg * 8);
    const f16x8 bf1 = *(const f16x8*)(W2t + (16 + col) * 40 + kg * 8);
    f32x4 ac0 = {0.f, 0.f, 0.f, 0.f}, ac1 = {0.f, 0.f, 0.f, 0.f};
    ac0 = __builtin_amdgcn_mfma_f32_16x16x32_f16(af, bf0, ac0, 0, 0, 0);
    ac1 = __builtin_amdgcn_mfma_f32_16x16x32_f16(af, bf1, ac1, 0, 0, 0);
    const float bb0 = b2[col], bb1 = b2[16 + col];
#pragma unroll
    for (int r = 0; r < 4; ++r) {
      const int m = m0 + kg * 4 + r;
      A1h[m * 40 + col] = f2h(fmaxf(ac0[r] + bb0, 0.f));
      A1h[m * 40 + 16 + col] = f2h(fmaxf(ac1[r] + bb1, 0.f));
    }
  }
  __syncthreads();
  const int c = t & 31;
  float rsum = 0.f, rq = 0.f;
#pragma unroll
  for (int rep = 0; rep < 8; ++rep) {
    const int row = (t >> 5) + rep * 8;
    const float v = h2f(A1h[row * 40 + c]);
    rsum += v;
    rq += v * v;
  }
  {
    const int row = t >> 2;
    const uint4 v = *(const uint4*)(A1h + row * 40 + (t & 3) * 8);
    *(uint4*)(yout + (size_t)(n0b + row) * 32 + (t & 3) * 8) = v;
  }
  rsum += __shfl_down(rsum, 32);
  rq += __shfl_down(rq, 32);
  __syncthreads();
  const int wv_ = t >> 6, lane = t & 63;
  if (lane < 32) {
    red[wv_ * 32 + lane] = rsum;
    red[128 + wv_ * 32 + lane] = rq;
  }
  __syncthreads();
  if (t < 32) {
    float aa = red[t] + red[32 + t] + red[64 + t] + red[96 + t];
    float bb = red[128 + t] + red[160 + t] + red[192 + t] + red[224 + t];
    unsafeAtomicAdd(&stats_out[t], aa);
    unsafeAtomicAdd(&stats_out[32 + t], bb);
  }
}

// ---- CNN body ----
__device__ __forceinline__ void cnn_body(
    int g, char* smem,
    const float* __restrict__ xo,
    const float* __restrict__ w1, const float* __restrict__ b1,
    const u16t* __restrict__ W2k, const float* __restrict__ b2,
    const u16t* __restrict__ W3k, const float* __restrict__ b3,
    u16t* __restrict__ t3)
{
  float* xot = (float*)(smem);
  float* w1s = (float*)(smem + 3072);
  float* b2s = (float*)(smem + 4096);
  float* b3s = (float*)(smem + 4352);
  short* T1T = (short*)(smem + 4864);
  char*  T2B = smem + 20736;
  u16t*  stg = (u16t*)(smem + 4864);

  const int t = threadIdx.x;
  const int w = t >> 6, l = t & 63, col = l & 15, kg = l >> 4;

  for (int i = t; i < 768; i += 256) xot[i] = (i < 735) ? xo[(size_t)g * 735 + i] : 0.f;
  w1s[t] = w1[t];
  if (t < 64) b2s[t] = b2[t];
  if (t < 128) b3s[t] = b3[t];
  if (t < 192) {
    int r = 242 + (t >> 5), c = t & 31;
    T1T[r * 32 + c] = 0;
  }
  __syncthreads();

  {
    const int c = t >> 3, qg = t & 7;
    float wv[8];
#pragma unroll
    for (int j = 0; j < 8; ++j) wv[j] = w1s[c * 8 + j];
    const float bias = b1[c];
    const int q0 = qg * 31, qe = (q0 + 31 < 242) ? q0 + 31 : 242;
#pragma unroll 1
    for (int qc = q0; qc < qe; qc += 10) {
      const int cnt = (qe - qc < 10) ? qe - qc : 10;
      float xv[37];
#pragma unroll
      for (int j = 0; j < 37; ++j) xv[j] = xot[3 * qc + j];
#pragma unroll
      for (int j0 = 0; j0 < 10; ++j0) {
        if (j0 < cnt) {
          float a0 = bias, a1 = bias, a2 = bias;
#pragma unroll
          for (int tt = 0; tt < 8; ++tt) {
            a0 = fmaf(wv[tt], xv[3 * j0 + tt], a0);
            a1 = fmaf(wv[tt], xv[3 * j0 + 1 + tt], a1);
            a2 = fmaf(wv[tt], xv[3 * j0 + 2 + tt], a2);
          }
          float m = fmaxf(fmaxf(a0, a1), fmaxf(a2, 0.f));
          const int pos = qc + j0;
          T1T[pos * 32 + (c ^ ((pos & 3) << 3))] = (short)f2bf(m);
        }
      }
    }
  }
  __syncthreads();

  {
    bf16x8 am[8];
#pragma unroll
    for (int kk = 0; kk < 8; ++kk)
      am[kk] = *(const bf16x8*)(W2k + (w * 16 + col) * 256 + kk * 32 + kg * 8);
#pragma unroll 1
    for (int qt = 0; qt < 5; ++qt) {
      const int rbase = qt * 48 + col * 3;
      bf16x8 rv[10];
#pragma unroll
      for (int s = 0; s < 10; ++s) {
        const int row = rbase + s;
        rv[s] = *(const bf16x8*)(T1T + row * 32 + ((kg ^ (row & 3)) << 3));
      }
      f32x4 a0 = {0.f, 0.f, 0.f, 0.f}, a1 = a0, a2 = a0;
#pragma unroll
      for (int kk = 0; kk < 8; ++kk) {
        a0 = __builtin_amdgcn_mfma_f32_16x16x32_bf16(am[kk], rv[kk], a0, 0, 0, 0);
        a1 = __builtin_amdgcn_mfma_f32_16x16x32_bf16(am[kk], rv[kk + 1], a1, 0, 0, 0);
        a2 = __builtin_amdgcn_mfma_f32_16x16x32_bf16(am[kk], rv[kk + 2], a2, 0, 0, 0);
      }
      const int q = qt * 16 + col;
      if (q < 78) {
        union { u16t u[4]; uint2 v; } pk;
#pragma unroll
        for (int r = 0; r < 4; ++r) {
          const float bb = b2s[w * 16 + kg * 4 + r];
          float m = fmaxf(fmaxf(a0[r], a1[r]), a2[r]);
          pk.u[r] = f2bf(fmaxf(m + bb, 0.f));
        }
        const int boff = (q * 128 + (w * 16 + kg * 4) * 2) ^ ((q & 7) << 4);
        *(uint2*)(T2B + boff) = pk.v;
      }
    }
  }
  __syncthreads();

  {
#pragma unroll 1
    for (int mi = 0; mi < 2; ++mi) {
      const int m3 = w * 2 + mi;
      f32x4 acc[2][3];
#pragma unroll
      for (int qt = 0; qt < 2; ++qt)
#pragma unroll
        for (int r = 0; r < 3; ++r) acc[qt][r] = (f32x4){0.f, 0.f, 0.f, 0.f};
#pragma unroll 1
      for (int kh = 0; kh < 2; ++kh) {
        bf16x8 amh[8];
#pragma unroll
        for (int tt = 0; tt < 8; ++tt)
          amh[tt] = *(const bf16x8*)(W3k + (m3 * 16 + col) * 512 + (tt * 2 + kh) * 32 + kg * 8);
#pragma unroll
        for (int qt = 0; qt < 2; ++qt) {
          const int rbase = qt * 48 + col * 3;
          bf16x8 rv[10];
#pragma unroll
          for (int s = 0; s < 10; ++s) {
            int row = rbase + s;
            row = (row < 78) ? row : 77;
            const int boff = (row * 128 + kh * 64 + kg * 16) ^ ((row & 7) << 4);
            rv[s] = *(const bf16x8*)(T2B + boff);
          }
#pragma unroll
          for (int tt = 0; tt < 8; ++tt) {
            acc[qt][0] = __builtin_amdgcn_mfma_f32_16x16x32_bf16(amh[tt], rv[tt], acc[qt][0], 0, 0, 0);
            acc[qt][1] = __builtin_amdgcn_mfma_f32_16x16x32_bf16(amh[tt], rv[tt + 1], acc[qt][1], 0, 0, 0);
            acc[qt][2] = __builtin_amdgcn_mfma_f32_16x16x32_bf16(amh[tt], rv[tt + 2], acc[qt][2], 0, 0, 0);
          }
        }
      }
#pragma unroll
      for (int qt = 0; qt < 2; ++qt) {
        const int q = qt * 16 + col;
        if (q < 23) {
#pragma unroll
          for (int r = 0; r < 4; ++r) {
            const int c = m3 * 16 + kg * 4 + r;
            float m = fmaxf(fmaxf(acc[qt][0][r], acc[qt][1][r]), acc[qt][2][r]);
            stg[c * 23 + q] = f2bf(fmaxf(m + b3s[c], 0.f));
          }
        }
      }
    }
  }
  __syncthreads();

  {
    const uint4* s4 = (const uint4*)stg;
    uint4* d4 = (uint4*)(t3 + (size_t)g * 2944);
    for (int id = t; id < 368; id += 256) d4[id] = s4[id];
  }
}

// ---- fused launch: 5 layer blocks + 2 cnn blocks per group of 7; 4 blocks/CU
// (5 blocks/CU caps VGPR at ~48 -> spills: WRITE 102->270MB, k_fused 295->328us. Keep 4.)
__global__ __launch_bounds__(256, 4) void k_fused(
    const u16t* __restrict__ yin, const u32t* __restrict__ rs, const int* __restrict__ ssrc,
    const float* __restrict__ stats, const float* __restrict__ gamma, const float* __restrict__ beta,
    const float* __restrict__ W1, const float* __restrict__ b1,
    const float* __restrict__ W2, const float* __restrict__ b2,
    u16t* __restrict__ yout, float* __restrict__ stats_out,
    const float* __restrict__ xo, const float* __restrict__ c1W, const float* __restrict__ c1b,
    const u16t* __restrict__ W2k, const float* __restrict__ c2b,
    const u16t* __restrict__ W3k, const float* __restrict__ c3b,
    u16t* __restrict__ t3, int cnn_g0)
{
  __shared__ __align__(16) char smem[30720];
  const int grp = blockIdx.x / 7, rem = blockIdx.x % 7;
  if (rem < 5)
    layer_body(grp * 5 + rem, smem, yin, rs, ssrc, stats, gamma, beta,
               W1, b1, W2, b2, yout, stats_out);
  else
    cnn_body(cnn_g0 + grp * 2 + (rem - 5), smem, xo, c1W, c1b, W2k, c2b, W3k, c3b, t3);
}

__global__ __launch_bounds__(64) void k_pool_xd(
    const u16t* __restrict__ y, const int* __restrict__ batch,
    const float* __restrict__ stats, const float* __restrict__ gamma,
    const float* __restrict__ beta, const float* __restrict__ Wxd,
    const float* __restrict__ bxd, u16t* __restrict__ xc)
{
  const int g = blockIdx.x, t = threadIdx.x;
  int lo = 0, n = NN;
  while (n > 0) {
    int h = n >> 1, m = lo + h;
    if (batch[m] < g) { lo = m + 1; n -= h + 1; } else n = h;
  }
  int hi = lo;
  n = NN - lo;
  while (n > 0) {
    int h = n >> 1, m = hi + h;
    if (batch[m] < g + 1) { hi = m + 1; n -= h + 1; } else n = h;
  }
  const int c = t & 31;
  const float mu = stats[4 * 64 + c] * (1.f / NN);
  float var = fmaxf(stats[4 * 64 + 32 + c] * (1.f / NN) - mu * mu, 0.f);
  const float sc = gamma[4 * 32 + c] * rsqrtf(var + BN_EPS);
  const float sh = beta[4 * 32 + c] - mu * sc;
  float acc = 0.f;
  for (int i = lo + (t >> 5); i < hi; i += 2) acc += h2f(y[(size_t)i * 32 + c]);
  acc += __shfl_down(acc, 32);
  __shared__ float pl[32];
  if (t < 32) pl[t] = acc * sc + (float)(hi - lo) * sh;
  __syncthreads();
#pragma unroll
  for (int rep = 0; rep < 2; ++rep) {
    const int o = t + rep * 64;
    float a = bxd[o];
#pragma unroll
    for (int cc = 0; cc < 32; ++cc) a = fmaf(pl[cc], Wxd[cc * 128 + o], a);
    xc[(size_t)g * 256 + o] = f2bf(fmaxf(a, 0.f));
  }
}

// ---------------- weight prep ----------------
__global__ __launch_bounds__(256) void k_prep(
    const float* __restrict__ w2, const float* __restrict__ w3,
    const float* __restrict__ wxt, const float* __restrict__ wf1, const float* __restrict__ wf2,
    u16t* __restrict__ W2k, u16t* __restrict__ W3k,
    u16t* __restrict__ WXT, u16t* __restrict__ WF1, u16t* __restrict__ WF2)
{
  const int i = blockIdx.x * 256 + threadIdx.x;
  if (i < 64 * 256) {
    int c2 = i >> 8, kk = i & 255, tt = kk >> 5, ci = kk & 31;
    W2k[i] = f2bf(w2[c2 * 256 + ci * 8 + tt]);
  }
  if (i < 128 * 512) {
    int c3 = i >> 9, kk = i & 511, tt = kk >> 6, ci = kk & 63;
    W3k[i] = f2bf(w3[c3 * 512 + ci * 8 + tt]);
  }
  if (i < 128 * 2944) {
    int nn = i / 2944, kk = i - nn * 2944;
    WXT[i] = f2bf(wxt[kk * 128 + nn]);
  }
  if (i < 1024 * 256) {
    int nn = i >> 8, kk = i & 255;
    WF1[i] = f2bf(wf1[kk * 1024 + nn]);
  }
  if (i < 128 * 1024) {
    int nn = i >> 10, kk = i & 1023;
    WF2[i] = f2bf(wf2[kk * 128 + nn]);
  }
}

// ---------------- bf16 MFMA GEMM ----------------
__global__ __launch_bounds__(256) void k_mgemm(
    const u16t* __restrict__ A, int lda,
    const u16t* __restrict__ WT, const float* __restrict__ bias,
    void* __restrict__ Cv, int ldc, int c_off, int M, int Kd,
    int relu_f, int out32)
{
  __shared__ __align__(16) u16t As[128 * 4 * 8];
  __shared__ __align__(16) u16t Ws2[64 * 4 * 8];
  const int t = threadIdx.x;
  const int w = t >> 6, l = t & 63, col = l & 15, kg = l >> 4;
  const int wm = w & 1, wn = w >> 1;
  const int m0 = blockIdx.x * 128, n0 = blockIdx.y * 64;
  f32x4 acc[4][2];
#pragma unroll
  for (int i = 0; i < 4; ++i)
#pragma unroll
    for (int j = 0; j < 2; ++j) acc[i][j] = (f32x4){0.f, 0.f, 0.f, 0.f};
  const int ar = t >> 1, ac = (t & 1) * 2;
  const int wr = t >> 2, wc = t & 3;
  const bool aok = (m0 + ar) < M;
  const u16t* Ap = A + (size_t)(m0 + ar) * lda;
  const u16t* Wp = WT + (size_t)(n0 + wr) * Kd;
  for (int k0 = 0; k0 < Kd; k0 += 32) {
    bf16x8 av0 = {0, 0, 0, 0, 0, 0, 0, 0}, av1 = {0, 0, 0, 0, 0, 0, 0, 0};
    if (aok) {
      av0 = *(const bf16x8*)(Ap + k0 + ac * 8);
      av1 = *(const bf16x8*)(Ap + k0 + (ac + 1) * 8);
    }
    const bf16x8 wv = *(const bf16x8*)(Wp + k0 + wc * 8);
    __syncthreads();
    *(bf16x8*)(As + (ar * 4 + (ac ^ (ar & 3))) * 8) = av0;
    *(bf16x8*)(As + (ar * 4 + ((ac + 1) ^ (ar & 3))) * 8) = av1;
    *(bf16x8*)(Ws2 + (wr * 4 + (wc ^ (wr & 3))) * 8) = wv;
    __syncthreads();
    bf16x8 af[4], bf[2];
#pragma unroll
    for (int i = 0; i < 4; ++i) {
      const int R = wm * 64 + i * 16 + col;
      af[i] = *(const bf16x8*)(As + (R * 4 + (kg ^ (R & 3))) * 8);
    }
#pragma unroll
    for (int j = 0; j < 2; ++j) {
      const int R = wn * 32 + j * 16 + col;
      bf[j] = *(const bf16x8*)(Ws2 + (R * 4 + (kg ^ (R & 3))) * 8);
    }
#pragma unroll
    for (int i = 0; i < 4; ++i)
#pragma unroll
      for (int j = 0; j < 2; ++j)
        acc[i][j] = __builtin_amdgcn_mfma_f32_16x16x32_bf16(af[i], bf[j], acc[i][j], 0, 0, 0);
  }
#pragma unroll
  for (int j = 0; j < 2; ++j) {
    const int gn = n0 + wn * 32 + j * 16 + col;
    const float bb = bias[gn];
#pragma unroll
    for (int i = 0; i < 4; ++i) {
      const int gmb = m0 + wm * 64 + i * 16 + kg * 4;
#pragma unroll
      for (int r = 0; r < 4; ++r) {
        const int gm = gmb + r;
        if (gm < M) {
          float v = acc[i][j][r] + bb;
          if (relu_f) v = fmaxf(v, 0.f);
          if (out32) ((float*)Cv)[(size_t)gm * ldc + c_off + gn] = v;
          else ((u16t*)Cv)[(size_t)gm * ldc + c_off + gn] = f2bf(v);
        }
      }
    }
  }
}

__global__ __launch_bounds__(256) void k_out(
    const float* __restrict__ h2, const float* __restrict__ Wo,
    const float* __restrict__ bo, float* __restrict__ out)
{
  __shared__ float Ws_[128];
  const int t = threadIdx.x;
  if (t < 128) Ws_[t] = Wo[t];
  __syncthreads();
  const int g = blockIdx.x * 32 + (t >> 3), l = t & 7;
  float acc = 0.f;
  if (g < NG) {
    const float* hr = h2 + (size_t)g * 128 + l * 16;
    const float* wr = Ws_ + l * 16;
#pragma unroll
    for (int j = 0; j < 16; ++j) acc = fmaf(hr[j], wr[j], acc);
  }
  acc += __shfl_down(acc, 4, 8);
  acc += __shfl_down(acc, 2, 8);
  acc += __shfl_down(acc, 1, 8);
  if (l == 0 && g < NG) out[g] = acc + bo[0];
}

extern "C" void kernel_launch(void* const* d_in, const int* in_sizes, int n_in,
                              void* d_out, int out_size, void* d_ws, size_t ws_size,
                              hipStream_t stream) {
  const float* x    = (const float*)d_in[0];
  const int*   ei   = (const int*)d_in[1];
  const int*   batch= (const int*)d_in[2];
  const float* xo   = (const float*)d_in[3];
  const float* g1W1 = (const float*)d_in[4];
  const float* g1b1 = (const float*)d_in[5];
  const float* g1W2 = (const float*)d_in[6];
  const float* g1b2 = (const float*)d_in[7];
  const float* gsW1 = (const float*)d_in[8];
  const float* gsb1 = (const float*)d_in[9];
  const float* gsW2 = (const float*)d_in[10];
  const float* gsb2 = (const float*)d_in[11];
  const float* bng  = (const float*)d_in[12];
  const float* bnb  = (const float*)d_in[13];
  const float* Wxd  = (const float*)d_in[14];
  const float* bxd  = (const float*)d_in[15];
  const float* c1W  = (const float*)d_in[16];
  const float* c1b  = (const float*)d_in[17];
  const float* c2W  = (const float*)d_in[18];
  const float* c2b  = (const float*)d_in[19];
  const float* c3W  = (const float*)d_in[20];
  const float* c3b  = (const float*)d_in[21];
  const float* Wxt  = (const float*)d_in[22];
  const float* bxt  = (const float*)d_in[23];
  const float* W1f  = (const float*)d_in[24];
  const float* b1f  = (const float*)d_in[25];
  const float* W2f  = (const float*)d_in[26];
  const float* b2f  = (const float*)d_in[27];
  const float* Wo   = (const float*)d_in[28];
  const float* bo   = (const float*)d_in[29];

  char* ws = (char*)d_ws;
  u16t*  U    = (u16t*)(ws + OFF_U);
  u16t*  YA   = (u16t*)(ws + OFF_YA);
  u16t*  YB   = (u16t*)(ws + OFF_YB);
  float* ST   = (float*)(ws + OFF_ST);
  u32t*  RS   = (u32t*)(ws + OFF_RS);
  u32t*  CUR  = (u32t*)(ws + OFF_CUR);
  u32t*  BS   = (u32t*)(ws + OFF_BSUM);
  int*   SSRC = (int*)(ws + OFF_SSRC);
  u16t*  WK   = (u16t*)(ws + OFF_WK);
  u16t*  W2K  = WK;
  u16t*  W3K  = WK + 16384;
  u16t*  WXT  = WK + 16384 + 65536;
  u16t*  WF1  = WK + 16384 + 65536 + 376832;
  u16t*  WF2  = WK + 16384 + 65536 + 376832 + 262144;
  u16t*  XC   = (u16t*)(ws + OFF_XC);
  u16t*  T3   = (u16t*)(ws + OFF_T3);
  u16t*  H1   = (u16t*)(ws + OFF_H1);
  float* H2   = (float*)(ws + OFF_H2);
  float* OUT  = (float*)d_out;

  const int NBLK = (NN + 1023) / 1024;

  hipMemsetAsync(ST, 0, 5 * 64 * sizeof(float), stream);
  hipMemsetAsync(CUR, 0, NN * sizeof(u32t), stream);

  k_prep<<<(128 * 2944 + 255) / 256, 256, 0, stream>>>(c2W, c3W, Wxt, W1f, W2f,
                                                        W2K, W3K, WXT, WF1, WF2);

  k_hist<<<(NE + 255) / 256, 256, 0, stream>>>(ei, CUR);
  k_scan1<<<NBLK, 256, 0, stream>>>(CUR, BS);
  k_scan2<<<1, 256, 0, stream>>>(BS, RS, NBLK);
  k_scan3<<<NBLK, 256, 0, stream>>>(CUR, RS, BS);
  for (int p = 0; p < 4; ++p)
    k_scatter<<<(NE + 255) / 256, 256, 0, stream>>>(ei, CUR, SSRC, p);

  k_mlp1_first<<<NN / 64, 256, 0, stream>>>(x, g1W1, U);
  k_agg0<<<NN / 64, 256, 0, stream>>>(U, RS, SSRC, g1b1, g1W2, g1b2, YA, ST + 0);

  const u16t* yin = YA;
  u16t* yout = YB;
  for (int lyr = 1; lyr <= 4; ++lyr) {
    k_fused<<<21875, 256, 0, stream>>>(yin, RS, SSRC, ST + (lyr - 1) * 64,
                                       bng + (lyr - 1) * 32, bnb + (lyr - 1) * 32,
                                       gsW1 + (lyr - 1) * 1024, gsb1 + (lyr - 1) * 32,
                                       gsW2 + (lyr - 1) * 1024, gsb2 + (lyr - 1) * 32,
                                       yout, ST + lyr * 64,
                                       xo, c1W, c1b, W2K, c2b, W3K, c3b, T3,
                                       (lyr - 1) * 6250);
    const u16t* tmp = yin;
    yin = yout;
    yout = (u16t*)tmp;
  }
  k_pool_xd<<<NG, 64, 0, stream>>>(yin, batch, ST, bng, bnb, Wxd, bxd, XC);

  {
    dim3 grid((NG + 127) / 128, 2);
    k_mgemm<<<grid, 256, 0, stream>>>(T3, 2944, WXT, bxt, XC, 256, 128, NG, 2944, 0, 0);
  }
  {
    dim3 grid((NG + 127) / 128, 16);
    k_mgemm<<<grid, 256, 0, stream>>>(XC, 256, WF1, b1f, H1, 1024, 0, NG, 256, 1, 0);
  }
  {
    dim3 grid((NG + 127) / 128, 2);
    k_mgemm<<<grid, 256, 0, stream>>>(H1, 1024, WF2, b2f, H2, 128, 0, NG, 1024, 1, 1);
  }
  k_out<<<(NG + 31) / 32, 256, 0, stream>>>(H2, Wo, bo, OUT);
}

// Round 19
// 1953.036 us; speedup vs baseline: 1.1081x; 1.0314x over previous
//
#include <hip/hip_runtime.h>

#define NN 1000000
#define NE 4000000
#define NG 25000
#define BN_EPS 1e-5f

typedef unsigned short u16t;
typedef unsigned int u32t;
typedef __attribute__((ext_vector_type(8))) short bf16x8;
typedef __attribute__((ext_vector_type(8))) _Float16 f16x8;
typedef __attribute__((ext_vector_type(4))) float f32x4;

__device__ inline u16t f2bf(float f) {
  u32t u = __float_as_uint(f);
  u32t r = (u + 0x7FFFu + ((u >> 16) & 1u)) >> 16;
  return (u16t)r;
}
__device__ inline float bf2f(u16t h) { return __uint_as_float((u32t)h << 16); }
__device__ inline u16t f2h(float f) {
  _Float16 h = (_Float16)f;
  return *(u16t*)&h;
}
__device__ inline float h2f(u16t v) {
  _Float16 h = *(_Float16*)&v;
  return (float)h;
}
__device__ inline void add8h(float* a, uint4 v) {
  union { uint4 u; _Float16 h[8]; } cv;
  cv.u = v;
#pragma unroll
  for (int j = 0; j < 8; ++j) a[j] += (float)cv.h[j];
}

// ---- workspace layout (bytes) ----
// T3 bf16 @0 (147.2MB) | YA @150e6 | YB @214e6 | ST @278e6 | RS @279e6 | CUR @283.2e6
// BSUM @287.3e6 | SSRC @288e6 (16MB) | WK @304e6 | XC @306e6 (12.8MB) | U @320e6 (64MB)
// U no longer overlaps T3 -> agg0 can fuse with CNN chunk 0.
// head: H1 @150e6 (over dead YA), H2 @214e6 (over dead YB)
static const size_t OFF_T3   = 0;
static const size_t OFF_YA   = 150000000;
static const size_t OFF_YB   = 214000000;
static const size_t OFF_ST   = 278000000;
static const size_t OFF_RS   = 279000000;
static const size_t OFF_CUR  = 283200000;
static const size_t OFF_BSUM = 287300000;
static const size_t OFF_SSRC = 288000000;
static const size_t OFF_WK   = 304000000;
static const size_t OFF_XC   = 306000000;
static const size_t OFF_U    = 320000000;
static const size_t OFF_H1   = 150000000;
static const size_t OFF_H2   = 214000000;

// ---------------- CSR build ----------------
__global__ __launch_bounds__(256) void k_hist(const int* __restrict__ ei, u32t* __restrict__ cnt) {
  const int i = blockIdx.x * 256 + threadIdx.x;
  if (i < NE) atomicAdd(&cnt[ei[NE + i]], 1u);
}

__global__ __launch_bounds__(256) void k_scan1(const u32t* __restrict__ deg, u32t* __restrict__ bsum) {
  __shared__ u32t red[4];
  const int b = blockIdx.x, t = threadIdx.x;
  u32t s = 0;
#pragma unroll
  for (int j = 0; j < 4; ++j) {
    const int i = b * 1024 + j * 256 + t;
    if (i < NN) s += deg[i];
  }
#pragma unroll
  for (int off = 32; off > 0; off >>= 1) s += __shfl_down(s, off);
  if ((t & 63) == 0) red[t >> 6] = s;
  __syncthreads();
  if (t == 0) bsum[b] = red[0] + red[1] + red[2] + red[3];
}

__global__ __launch_bounds__(256) void k_scan2(u32t* __restrict__ bsum, u32t* __restrict__ rs, int nblk) {
  __shared__ u32t sh[256];
  const int t = threadIdx.x;
  u32t v[4];
#pragma unroll
  for (int j = 0; j < 4; ++j) {
    const int i = t * 4 + j;
    v[j] = (i < nblk) ? bsum[i] : 0u;
  }
  const u32t tot = v[0] + v[1] + v[2] + v[3];
  sh[t] = tot;
  __syncthreads();
  for (int off = 1; off < 256; off <<= 1) {
    u32t add = (t >= off) ? sh[t - off] : 0u;
    __syncthreads();
    sh[t] += add;
    __syncthreads();
  }
  const u32t tb = (t == 0) ? 0u : sh[t - 1];
  u32t run = tb;
#pragma unroll
  for (int j = 0; j < 4; ++j) {
    const int i = t * 4 + j;
    if (i < nblk) bsum[i] = run;
    run += v[j];
  }
  if (t == 0) rs[NN] = NE;
}

__global__ __launch_bounds__(256) void k_scan3(u32t* __restrict__ cur, u32t* __restrict__ rs,
                                               const u32t* __restrict__ bsum) {
  __shared__ u32t sh[256];
  const int b = blockIdx.x, t = threadIdx.x;
  const int i0 = b * 1024 + t * 4;
  u32t v[4];
#pragma unroll
  for (int j = 0; j < 4; ++j) v[j] = (i0 + j < NN) ? cur[i0 + j] : 0u;
  sh[t] = v[0] + v[1] + v[2] + v[3];
  __syncthreads();
  for (int off = 1; off < 256; off <<= 1) {
    u32t add = (t >= off) ? sh[t - off] : 0u;
    __syncthreads();
    sh[t] += add;
    __syncthreads();
  }
  u32t run = bsum[b] + ((t == 0) ? 0u : sh[t - 1]);
#pragma unroll
  for (int j = 0; j < 4; ++j) {
    const int i = i0 + j;
    if (i < NN) { rs[i] = run; cur[i] = run; }
    run += v[j];
  }
}

// dst-range-partitioned scatter: pass p handles dst>>17 == p (8 passes).
__global__ __launch_bounds__(256) void k_scatter(const int* __restrict__ ei,
                                                 u32t* __restrict__ cur, int* __restrict__ ssrc,
                                                 int pass) {
  const int i = blockIdx.x * 256 + threadIdx.x;
  if (i < NE) {
    const int dst = ei[NE + i];
    if ((dst >> 17) == pass) {
      const int src = ei[i];
      const u32t pos = atomicAdd(&cur[dst], 1u);
      ssrc[pos] = src;
    }
  }
}

// ---------------- GNN kernels ----------------

__global__ __launch_bounds__(256) void k_mlp1_first(
    const float* __restrict__ x, const float* __restrict__ W1, u16t* __restrict__ u)
{
  __shared__ __align__(16) u16t Xh[64 * 104];
  __shared__ __align__(16) u16t Wt[32 * 104];
  __shared__ __align__(16) u16t Uh[64 * 40];
  const int t = threadIdx.x;
  const int n0b = blockIdx.x * 64;
  for (int id = t; id < 64 * 78; id += 256) {
    const int row = id / 78, k = id - row * 78;
    Xh[row * 104 + k] = f2h(x[(size_t)n0b * 78 + id]);
  }
  for (int id = t; id < 64 * 18; id += 256) {
    const int row = id / 18, k = 78 + (id - row * 18);
    Xh[row * 104 + k] = 0;
  }
  for (int id = t; id < 78 * 32; id += 256) {
    const int k = id >> 5, c = id & 31;
    Wt[c * 104 + k] = f2h(W1[id]);
  }
  for (int id = t; id < 32 * 18; id += 256) {
    const int c = id / 18, k = 78 + (id - c * 18);
    Wt[c * 104 + k] = 0;
  }
  __syncthreads();
  {
    const int w = t >> 6, l = t & 63, col = l & 15, kg = l >> 4;
    const int m0 = w * 16;
    f32x4 ac0 = {0.f, 0.f, 0.f, 0.f}, ac1 = {0.f, 0.f, 0.f, 0.f};
#pragma unroll
    for (int ks = 0; ks < 3; ++ks) {
      const f16x8 af = *(const f16x8*)(Xh + (m0 + col) * 104 + ks * 32 + kg * 8);
      const f16x8 bf0 = *(const f16x8*)(Wt + col * 104 + ks * 32 + kg * 8);
      const f16x8 bf1 = *(const f16x8*)(Wt + (16 + col) * 104 + ks * 32 + kg * 8);
      ac0 = __builtin_amdgcn_mfma_f32_16x16x32_f16(af, bf0, ac0, 0, 0, 0);
      ac1 = __builtin_amdgcn_mfma_f32_16x16x32_f16(af, bf1, ac1, 0, 0, 0);
    }
#pragma unroll
    for (int r = 0; r < 4; ++r) {
      const int m = m0 + kg * 4 + r;
      Uh[m * 40 + col] = f2h(ac0[r]);
      Uh[m * 40 + 16 + col] = f2h(ac1[r]);
    }
  }
  __syncthreads();
  {
    const int row = t >> 2;
    const uint4 v = *(const uint4*)(Uh + row * 40 + (t & 3) * 8);
    *(uint4*)(u + (size_t)(n0b + row) * 32 + (t & 3) * 8) = v;
  }
}

// ---- agg0 body (layer 0 part B), shared LDS arena ----
__device__ __forceinline__ void agg0_body(
    int bid, char* smem,
    const u16t* __restrict__ u, const u32t* __restrict__ rs, const int* __restrict__ ssrc,
    const float* __restrict__ b1, const float* __restrict__ W2, const float* __restrict__ b2,
    u16t* __restrict__ yout, float* __restrict__ stats_out)
{
  u16t* W2t = (u16t*)(smem + 2560);
  u16t* A1h = (u16t*)(smem + 5120);
  u16t* A2h = (u16t*)(smem + 10240);
  float* red = (float*)(smem + 15360);
  u32t* rss = (u32t*)(smem + 16384);
  const int t = threadIdx.x;
  const int n0b = bid * 64;
  for (int id = t; id < 1024; id += 256) {
    int k = id >> 5, c = id & 31;
    W2t[c * 40 + k] = f2h(W2[id]);
  }
  if (t < 65) rss[t] = rs[n0b + t];
  __syncthreads();
  const int nl = t >> 2, c0 = (t & 3) * 8;
  {
    const int n = n0b + nl;
    float a[8] = {};
    add8h(a, *(const uint4*)(u + (size_t)n * 32 + c0));
    const u32t e0 = rss[nl], e1 = rss[nl + 1];
    u32t e = e0;
    for (; e + 4 <= e1; e += 4) {
      const int s0v = ssrc[e], s1v = ssrc[e + 1], s2v = ssrc[e + 2], s3v = ssrc[e + 3];
      const uint4 v0 = *(const uint4*)(u + (size_t)s0v * 32 + c0);
      const uint4 v1 = *(const uint4*)(u + (size_t)s1v * 32 + c0);
      const uint4 v2 = *(const uint4*)(u + (size_t)s2v * 32 + c0);
      const uint4 v3 = *(const uint4*)(u + (size_t)s3v * 32 + c0);
      add8h(a, v0); add8h(a, v1); add8h(a, v2); add8h(a, v3);
    }
    for (; e < e1; ++e)
      add8h(a, *(const uint4*)(u + (size_t)ssrc[e] * 32 + c0));
    union { u16t h[8]; uint4 v; } pk;
#pragma unroll
    for (int j = 0; j < 8; ++j) pk.h[j] = f2h(fmaxf(a[j] + b1[c0 + j], 0.f));
    *(uint4*)(A1h + nl * 40 + c0) = pk.v;
  }
  __syncthreads();
  {
    const int w = t >> 6, l = t & 63, col = l & 15, kg = l >> 4;
    const int m0 = w * 16;
    const f16x8 af = *(const f16x8*)(A1h + (m0 + col) * 40 + kg * 8);
    const f16x8 bf0 = *(const f16x8*)(W2t + col * 40 + kg * 8);
    const f16x8 bf1 = *(const f16x8*)(W2t + (16 + col) * 40 + kg * 8);
    f32x4 ac0 = {0.f, 0.f, 0.f, 0.f}, ac1 = {0.f, 0.f, 0.f, 0.f};
    ac0 = __builtin_amdgcn_mfma_f32_16x16x32_f16(af, bf0, ac0, 0, 0, 0);
    ac1 = __builtin_amdgcn_mfma_f32_16x16x32_f16(af, bf1, ac1, 0, 0, 0);
    const float bb0 = b2[col], bb1 = b2[16 + col];
#pragma unroll
    for (int r = 0; r < 4; ++r) {
      const int m = m0 + kg * 4 + r;
      A2h[m * 40 + col] = f2h(fmaxf(ac0[r] + bb0, 0.f));
      A2h[m * 40 + 16 + col] = f2h(fmaxf(ac1[r] + bb1, 0.f));
    }
  }
  __syncthreads();
  const int c = t & 31;
  float rsum = 0.f, rq = 0.f;
#pragma unroll
  for (int rep = 0; rep < 8; ++rep) {
    const int row = (t >> 5) + rep * 8;
    const float v = h2f(A2h[row * 40 + c]);
    rsum += v;
    rq += v * v;
  }
  {
    const int row = t >> 2;
    const uint4 v = *(const uint4*)(A2h + row * 40 + (t & 3) * 8);
    *(uint4*)(yout + (size_t)(n0b + row) * 32 + (t & 3) * 8) = v;
  }
  rsum += __shfl_down(rsum, 32);
  rq += __shfl_down(rq, 32);
  __syncthreads();
  const int wv_ = t >> 6, lane = t & 63;
  if (lane < 32) {
    red[wv_ * 32 + lane] = rsum;
    red[128 + wv_ * 32 + lane] = rq;
  }
  __syncthreads();
  if (t < 32) {
    float aa = red[t] + red[32 + t] + red[64 + t] + red[96 + t];
    float bb = red[128 + t] + red[160 + t] + red[192 + t] + red[224 + t];
    unsafeAtomicAdd(&stats_out[t], aa);
    unsafeAtomicAdd(&stats_out[32 + t], bb);
  }
}

// ---- layer body (layers 1..4) ----
__device__ __forceinline__ void layer_body(
    int bid, char* smem,
    const u16t* __restrict__ yin, const u32t* __restrict__ rs, const int* __restrict__ ssrc,
    const float* __restrict__ stats, const float* __restrict__ gamma, const float* __restrict__ beta,
    const float* __restrict__ W1, const float* __restrict__ b1,
    const float* __restrict__ W2, const float* __restrict__ b2,
    u16t* __restrict__ yout, float* __restrict__ stats_out)
{
  u16t* W1t = (u16t*)smem;
  u16t* W2t = (u16t*)(smem + 2560);
  u16t* A1h = (u16t*)(smem + 5120);
  u16t* A2h = (u16t*)(smem + 10240);
  float* red = (float*)(smem + 15360);
  u32t* rss = (u32t*)(smem + 16384);
  const int t = threadIdx.x;
  const int n0b = bid * 64;
  for (int id = t; id < 1024; id += 256) {
    int k = id >> 5, c = id & 31;
    W1t[c * 40 + k] = f2h(W1[id]);
    W2t[c * 40 + k] = f2h(W2[id]);
  }
  if (t < 65) rss[t] = rs[n0b + t];
  __syncthreads();
  const int nl = t >> 2, c0 = (t & 3) * 8;
  {
    const int n = n0b + nl;
    float sc[8], sh[8];
#pragma unroll
    for (int j = 0; j < 8; ++j) {
      const int c = c0 + j;
      const float mu = stats[c] * (1.f / NN);
      float var = fmaxf(stats[32 + c] * (1.f / NN) - mu * mu, 0.f);
      sc[j] = gamma[c] * rsqrtf(var + BN_EPS);
      sh[j] = beta[c] - mu * sc[j];
    }
    float a[8] = {};
    add8h(a, *(const uint4*)(yin + (size_t)n * 32 + c0));
    const u32t e0 = rss[nl], e1 = rss[nl + 1];
    u32t e = e0;
    for (; e + 4 <= e1; e += 4) {
      const int s0v = ssrc[e], s1v = ssrc[e + 1], s2v = ssrc[e + 2], s3v = ssrc[e + 3];
      const uint4 v0 = *(const uint4*)(yin + (size_t)s0v * 32 + c0);
      const uint4 v1 = *(const uint4*)(yin + (size_t)s1v * 32 + c0);
      const uint4 v2 = *(const uint4*)(yin + (size_t)s2v * 32 + c0);
      const uint4 v3 = *(const uint4*)(yin + (size_t)s3v * 32 + c0);
      add8h(a, v0); add8h(a, v1); add8h(a, v2); add8h(a, v3);
    }
    for (; e < e1; ++e)
      add8h(a, *(const uint4*)(yin + (size_t)ssrc[e] * 32 + c0));
    const float cnt = (float)(e1 - e0 + 1u);
    union { u16t h[8]; uint4 v; } pk;
#pragma unroll
    for (int j = 0; j < 8; ++j) pk.h[j] = f2h(sc[j] * a[j] + cnt * sh[j]);
    *(uint4*)(A1h + nl * 40 + c0) = pk.v;
  }
  __syncthreads();
  const int w = t >> 6, l = t & 63, col = l & 15, kg = l >> 4;
  const int m0 = w * 16;
  {
    const f16x8 af = *(const f16x8*)(A1h + (m0 + col) * 40 + kg * 8);
    const f16x8 bf0 = *(const f16x8*)(W1t + col * 40 + kg * 8);
    const f16x8 bf1 = *(const f16x8*)(W1t + (16 + col) * 40 + kg * 8);
    f32x4 ac0 = {0.f, 0.f, 0.f, 0.f}, ac1 = {0.f, 0.f, 0.f, 0.f};
    ac0 = __builtin_amdgcn_mfma_f32_16x16x32_f16(af, bf0, ac0, 0, 0, 0);
    ac1 = __builtin_amdgcn_mfma_f32_16x16x32_f16(af, bf1, ac1, 0, 0, 0);
    const float bb0 = b1[col], bb1 = b1[16 + col];
#pragma unroll
    for (int r = 0; r < 4; ++r) {
      const int m = m0 + kg * 4 + r;
      A2h[m * 40 + col] = f2h(fmaxf(ac0[r] + bb0, 0.f));
      A2h[m * 40 + 16 + col] = f2h(fmaxf(ac1[r] + bb1, 0.f));
    }
  }
  __syncthreads();
  {
    const f16x8 af = *(const f16x8*)(A2h + (m0 + col) * 40 + kg * 8);
    const f16x8 bf0 = *(const f16x8*)(W2t + col * 40 + kg * 8);
    const f16x8 bf1 = *(const f16x8*)(W2t + (16 + col) * 40 + kg * 8);
    f32x4 ac0 = {0.f, 0.f, 0.f, 0.f}, ac1 = {0.f, 0.f, 0.f, 0.f};
    ac0 = __builtin_amdgcn_mfma_f32_16x16x32_f16(af, bf0, ac0, 0, 0, 0);
    ac1 = __builtin_amdgcn_mfma_f32_16x16x32_f16(af, bf1, ac1, 0, 0, 0);
    const float bb0 = b2[col], bb1 = b2[16 + col];
#pragma unroll
    for (int r = 0; r < 4; ++r) {
      const int m = m0 + kg * 4 + r;
      A1h[m * 40 + col] = f2h(fmaxf(ac0[r] + bb0, 0.f));
      A1h[m * 40 + 16 + col] = f2h(fmaxf(ac1[r] + bb1, 0.f));
    }
  }
  __syncthreads();
  const int c = t & 31;
  float rsum = 0.f, rq = 0.f;
#pragma unroll
  for (int rep = 0; rep < 8; ++rep) {
    const int row = (t >> 5) + rep * 8;
    const float v = h2f(A1h[row * 40 + c]);
    rsum += v;
    rq += v * v;
  }
  {
    const int row = t >> 2;
    const uint4 v = *(const uint4*)(A1h + row * 40 + (t & 3) * 8);
    *(uint4*)(yout + (size_t)(n0b + row) * 32 + (t & 3) * 8) = v;
  }
  rsum += __shfl_down(rsum, 32);
  rq += __shfl_down(rq, 32);
  __syncthreads();
  const int wv_ = t >> 6, lane = t & 63;
  if (lane < 32) {
    red[wv_ * 32 + lane] = rsum;
    red[128 + wv_ * 32 + lane] = rq;
  }
  __syncthreads();
  if (t < 32) {
    float aa = red[t] + red[32 + t] + red[64 + t] + red[96 + t];
    float bb = red[128 + t] + red[160 + t] + red[192 + t] + red[224 + t];
    unsafeAtomicAdd(&stats_out[t], aa);
    unsafeAtomicAdd(&stats_out[32 + t], bb);
  }
}

// ---- CNN body ----
__device__ __forceinline__ void cnn_body(
    int g, char* smem,
    const float* __restrict__ xo,
    const float* __restrict__ w1, const float* __restrict__ b1,
    const u16t* __restrict__ W2k, const float* __restrict__ b2,
    const u16t* __restrict__ W3k, const float* __restrict__ b3,
    u16t* __restrict__ t3)
{
  float* xot = (float*)(smem);
  float* w1s = (float*)(smem + 3072);
  float* b2s = (float*)(smem + 4096);
  float* b3s = (float*)(smem + 4352);
  short* T1T = (short*)(smem + 4864);
  char*  T2B = smem + 20736;
  u16t*  stg = (u16t*)(smem + 4864);

  const int t = threadIdx.x;
  const int w = t >> 6, l = t & 63, col = l & 15, kg = l >> 4;

  for (int i = t; i < 768; i += 256) xot[i] = (i < 735) ? xo[(size_t)g * 735 + i] : 0.f;
  w1s[t] = w1[t];
  if (t < 64) b2s[t] = b2[t];
  if (t < 128) b3s[t] = b3[t];
  if (t < 192) {
    int r = 242 + (t >> 5), c = t & 31;
    T1T[r * 32 + c] = 0;
  }
  __syncthreads();

  {
    const int c = t >> 3, qg = t & 7;
    float wv[8];
#pragma unroll
    for (int j = 0; j < 8; ++j) wv[j] = w1s[c * 8 + j];
    const float bias = b1[c];
    const int q0 = qg * 31, qe = (q0 + 31 < 242) ? q0 + 31 : 242;
#pragma unroll 1
    for (int qc = q0; qc < qe; qc += 10) {
      const int cnt = (qe - qc < 10) ? qe - qc : 10;
      float xv[37];
#pragma unroll
      for (int j = 0; j < 37; ++j) xv[j] = xot[3 * qc + j];
#pragma unroll
      for (int j0 = 0; j0 < 10; ++j0) {
        if (j0 < cnt) {
          float a0 = bias, a1 = bias, a2 = bias;
#pragma unroll
          for (int tt = 0; tt < 8; ++tt) {
            a0 = fmaf(wv[tt], xv[3 * j0 + tt], a0);
            a1 = fmaf(wv[tt], xv[3 * j0 + 1 + tt], a1);
            a2 = fmaf(wv[tt], xv[3 * j0 + 2 + tt], a2);
          }
          float m = fmaxf(fmaxf(a0, a1), fmaxf(a2, 0.f));
          const int pos = qc + j0;
          T1T[pos * 32 + (c ^ ((pos & 3) << 3))] = (short)f2bf(m);
        }
      }
    }
  }
  __syncthreads();

  {
    bf16x8 am[8];
#pragma unroll
    for (int kk = 0; kk < 8; ++kk)
      am[kk] = *(const bf16x8*)(W2k + (w * 16 + col) * 256 + kk * 32 + kg * 8);
#pragma unroll 1
    for (int qt = 0; qt < 5; ++qt) {
      const int rbase = qt * 48 + col * 3;
      bf16x8 rv[10];
#pragma unroll
      for (int s = 0; s < 10; ++s) {
        const int row = rbase + s;
        rv[s] = *(const bf16x8*)(T1T + row * 32 + ((kg ^ (row & 3)) << 3));
      }
      f32x4 a0 = {0.f, 0.f, 0.f, 0.f}, a1 = a0, a2 = a0;
#pragma unroll
      for (int kk = 0; kk < 8; ++kk) {
        a0 = __builtin_amdgcn_mfma_f32_16x16x32_bf16(am[kk], rv[kk], a0, 0, 0, 0);
        a1 = __builtin_amdgcn_mfma_f32_16x16x32_bf16(am[kk], rv[kk + 1], a1, 0, 0, 0);
        a2 = __builtin_amdgcn_mfma_f32_16x16x32_bf16(am[kk], rv[kk + 2], a2, 0, 0, 0);
      }
      const int q = qt * 16 + col;
      if (q < 78) {
        union { u16t u[4]; uint2 v; } pk;
#pragma unroll
        for (int r = 0; r < 4; ++r) {
          const float bb = b2s[w * 16 + kg * 4 + r];
          float m = fmaxf(fmaxf(a0[r], a1[r]), a2[r]);
          pk.u[r] = f2bf(fmaxf(m + bb, 0.f));
        }
        const int boff = (q * 128 + (w * 16 + kg * 4) * 2) ^ ((q & 7) << 4);
        *(uint2*)(T2B + boff) = pk.v;
      }
    }
  }
  __syncthreads();

  {
#pragma unroll 1
    for (int mi = 0; mi < 2; ++mi) {
      const int m3 = w * 2 + mi;
      f32x4 acc[2][3];
#pragma unroll
      for (int qt = 0; qt < 2; ++qt)
#pragma unroll
        for (int r = 0; r < 3; ++r) acc[qt][r] = (f32x4){0.f, 0.f, 0.f, 0.f};
#pragma unroll 1
      for (int kh = 0; kh < 2; ++kh) {
        bf16x8 amh[8];
#pragma unroll
        for (int tt = 0; tt < 8; ++tt)
          amh[tt] = *(const bf16x8*)(W3k + (m3 * 16 + col) * 512 + (tt * 2 + kh) * 32 + kg * 8);
#pragma unroll
        for (int qt = 0; qt < 2; ++qt) {
          const int rbase = qt * 48 + col * 3;
          bf16x8 rv[10];
#pragma unroll
          for (int s = 0; s < 10; ++s) {
            int row = rbase + s;
            row = (row < 78) ? row : 77;
            const int boff = (row * 128 + kh * 64 + kg * 16) ^ ((row & 7) << 4);
            rv[s] = *(const bf16x8*)(T2B + boff);
          }
#pragma unroll
          for (int tt = 0; tt < 8; ++tt) {
            acc[qt][0] = __builtin_amdgcn_mfma_f32_16x16x32_bf16(amh[tt], rv[tt], acc[qt][0], 0, 0, 0);
            acc[qt][1] = __builtin_amdgcn_mfma_f32_16x16x32_bf16(amh[tt], rv[tt + 1], acc[qt][1], 0, 0, 0);
            acc[qt][2] = __builtin_amdgcn_mfma_f32_16x16x32_bf16(amh[tt], rv[tt + 2], acc[qt][2], 0, 0, 0);
          }
        }
      }
#pragma unroll
      for (int qt = 0; qt < 2; ++qt) {
        const int q = qt * 16 + col;
        if (q < 23) {
#pragma unroll
          for (int r = 0; r < 4; ++r) {
            const int c = m3 * 16 + kg * 4 + r;
            float m = fmaxf(fmaxf(acc[qt][0][r], acc[qt][1][r]), acc[qt][2][r]);
            stg[c * 23 + q] = f2bf(fmaxf(m + b3s[c], 0.f));
          }
        }
      }
    }
  }
  __syncthreads();

  {
    const uint4* s4 = (const uint4*)stg;
    uint4* d4 = (uint4*)(t3 + (size_t)g * 2944);
    for (int id = t; id < 368; id += 256) d4[id] = s4[id];
  }
}

// ---- fused agg0 + CNN chunk: 25 agg blocks + 8 cnn blocks per group of 33 ----
__global__ __launch_bounds__(256, 4) void k_fused0(
    const u16t* __restrict__ u, const u32t* __restrict__ rs, const int* __restrict__ ssrc,
    const float* __restrict__ b1, const float* __restrict__ W2, const float* __restrict__ b2,
    u16t* __restrict__ yout, float* __restrict__ stats_out,
    const float* __restrict__ xo, const float* __restrict__ c1W, const float* __restrict__ c1b,
    const u16t* __restrict__ W2k, const float* __restrict__ c2b,
    const u16t* __restrict__ W3k, const float* __restrict__ c3b,
    u16t* __restrict__ t3, int cnn_g0)
{
  __shared__ __align__(16) char smem[30720];
  const int grp = blockIdx.x / 33, rem = blockIdx.x % 33;
  if (rem < 25)
    agg0_body(grp * 25 + rem, smem, u, rs, ssrc, b1, W2, b2, yout, stats_out);
  else
    cnn_body(cnn_g0 + grp * 8 + (rem - 25), smem, xo, c1W, c1b, W2k, c2b, W3k, c3b, t3);
}

// ---- fused layer + CNN chunk: 25 layer blocks + 8 cnn blocks per group of 33 ----
__global__ __launch_bounds__(256, 4) void k_fused(
    const u16t* __restrict__ yin, const u32t* __restrict__ rs, const int* __restrict__ ssrc,
    const float* __restrict__ stats, const float* __restrict__ gamma, const float* __restrict__ beta,
    const float* __restrict__ W1, const float* __restrict__ b1,
    const float* __restrict__ W2, const float* __restrict__ b2,
    u16t* __restrict__ yout, float* __restrict__ stats_out,
    const float* __restrict__ xo, const float* __restrict__ c1W, const float* __restrict__ c1b,
    const u16t* __restrict__ W2k, const float* __restrict__ c2b,
    const u16t* __restrict__ W3k, const float* __restrict__ c3b,
    u16t* __restrict__ t3, int cnn_g0)
{
  __shared__ __align__(16) char smem[30720];
  const int grp = blockIdx.x / 33, rem = blockIdx.x % 33;
  if (rem < 25)
    layer_body(grp * 25 + rem, smem, yin, rs, ssrc, stats, gamma, beta,
               W1, b1, W2, b2, yout, stats_out);
  else
    cnn_body(cnn_g0 + grp * 8 + (rem - 25), smem, xo, c1W, c1b, W2k, c2b, W3k, c3b, t3);
}

__global__ __launch_bounds__(64) void k_pool_xd(
    const u16t* __restrict__ y, const int* __restrict__ batch,
    const float* __restrict__ stats, const float* __restrict__ gamma,
    const float* __restrict__ beta, const float* __restrict__ Wxd,
    const float* __restrict__ bxd, u16t* __restrict__ xc)
{
  const int g = blockIdx.x, t = threadIdx.x;
  int lo = 0, n = NN;
  while (n > 0) {
    int h = n >> 1, m = lo + h;
    if (batch[m] < g) { lo = m + 1; n -= h + 1; } else n = h;
  }
  int hi = lo;
  n = NN - lo;
  while (n > 0) {
    int h = n >> 1, m = hi + h;
    if (batch[m] < g + 1) { hi = m + 1; n -= h + 1; } else n = h;
  }
  const int c = t & 31;
  const float mu = stats[4 * 64 + c] * (1.f / NN);
  float var = fmaxf(stats[4 * 64 + 32 + c] * (1.f / NN) - mu * mu, 0.f);
  const float sc = gamma[4 * 32 + c] * rsqrtf(var + BN_EPS);
  const float sh = beta[4 * 32 + c] - mu * sc;
  float acc = 0.f;
  for (int i = lo + (t >> 5); i < hi; i += 2) acc += h2f(y[(size_t)i * 32 + c]);
  acc += __shfl_down(acc, 32);
  __shared__ float pl[32];
  if (t < 32) pl[t] = acc * sc + (float)(hi - lo) * sh;
  __syncthreads();
#pragma unroll
  for (int rep = 0; rep < 2; ++rep) {
    const int o = t + rep * 64;
    float a = bxd[o];
#pragma unroll
    for (int cc = 0; cc < 32; ++cc) a = fmaf(pl[cc], Wxd[cc * 128 + o], a);
    xc[(size_t)g * 256 + o] = f2bf(fmaxf(a, 0.f));
  }
}

// ---------------- weight prep ----------------
__global__ __launch_bounds__(256) void k_prep(
    const float* __restrict__ w2, const float* __restrict__ w3,
    const float* __restrict__ wxt, const float* __restrict__ wf1, const float* __restrict__ wf2,
    u16t* __restrict__ W2k, u16t* __restrict__ W3k,
    u16t* __restrict__ WXT, u16t* __restrict__ WF1, u16t* __restrict__ WF2)
{
  const int i = blockIdx.x * 256 + threadIdx.x;
  if (i < 64 * 256) {
    int c2 = i >> 8, kk = i & 255, tt = kk >> 5, ci = kk & 31;
    W2k[i] = f2bf(w2[c2 * 256 + ci * 8 + tt]);
  }
  if (i < 128 * 512) {
    int c3 = i >> 9, kk = i & 511, tt = kk >> 6, ci = kk & 63;
    W3k[i] = f2bf(w3[c3 * 512 + ci * 8 + tt]);
  }
  if (i < 128 * 2944) {
    int nn = i / 2944, kk = i - nn * 2944;
    WXT[i] = f2bf(wxt[kk * 128 + nn]);
  }
  if (i < 1024 * 256) {
    int nn = i >> 8, kk = i & 255;
    WF1[i] = f2bf(wf1[kk * 1024 + nn]);
  }
  if (i < 128 * 1024) {
    int nn = i >> 10, kk = i & 1023;
    WF2[i] = f2bf(wf2[kk * 128 + nn]);
  }
}

// ---------------- bf16 MFMA GEMM ----------------
__global__ __launch_bounds__(256) void k_mgemm(
    const u16t* __restrict__ A, int lda,
    const u16t* __restrict__ WT, const float* __restrict__ bias,
    void* __restrict__ Cv, int ldc, int c_off, int M, int Kd,
    int relu_f, int out32)
{
  __shared__ __align__(16) u16t As[128 * 4 * 8];
  __shared__ __align__(16) u16t Ws2[64 * 4 * 8];
  const int t = threadIdx.x;
  const int w = t >> 6, l = t & 63, col = l & 15, kg = l >> 4;
  const int wm = w & 1, wn = w >> 1;
  const int m0 = blockIdx.x * 128, n0 = blockIdx.y * 64;
  f32x4 acc[4][2];
#pragma unroll
  for (int i = 0; i < 4; ++i)
#pragma unroll
    for (int j = 0; j < 2; ++j) acc[i][j] = (f32x4){0.f, 0.f, 0.f, 0.f};
  const int ar = t >> 1, ac = (t & 1) * 2;
  const int wr = t >> 2, wc = t & 3;
  const bool aok = (m0 + ar) < M;
  const u16t* Ap = A + (size_t)(m0 + ar) * lda;
  const u16t* Wp = WT + (size_t)(n0 + wr) * Kd;
  for (int k0 = 0; k0 < Kd; k0 += 32) {
    bf16x8 av0 = {0, 0, 0, 0, 0, 0, 0, 0}, av1 = {0, 0, 0, 0, 0, 0, 0, 0};
    if (aok) {
      av0 = *(const bf16x8*)(Ap + k0 + ac * 8);
      av1 = *(const bf16x8*)(Ap + k0 + (ac + 1) * 8);
    }
    const bf16x8 wv = *(const bf16x8*)(Wp + k0 + wc * 8);
    __syncthreads();
    *(bf16x8*)(As + (ar * 4 + (ac ^ (ar & 3))) * 8) = av0;
    *(bf16x8*)(As + (ar * 4 + ((ac + 1) ^ (ar & 3))) * 8) = av1;
    *(bf16x8*)(Ws2 + (wr * 4 + (wc ^ (wr & 3))) * 8) = wv;
    __syncthreads();
    bf16x8 af[4], bf[2];
#pragma unroll
    for (int i = 0; i < 4; ++i) {
      const int R = wm * 64 + i * 16 + col;
      af[i] = *(const bf16x8*)(As + (R * 4 + (kg ^ (R & 3))) * 8);
    }
#pragma unroll
    for (int j = 0; j < 2; ++j) {
      const int R = wn * 32 + j * 16 + col;
      bf[j] = *(const bf16x8*)(Ws2 + (R * 4 + (kg ^ (R & 3))) * 8);
    }
#pragma unroll
    for (int i = 0; i < 4; ++i)
#pragma unroll
      for (int j = 0; j < 2; ++j)
        acc[i][j] = __builtin_amdgcn_mfma_f32_16x16x32_bf16(af[i], bf[j], acc[i][j], 0, 0, 0);
  }
#pragma unroll
  for (int j = 0; j < 2; ++j) {
    const int gn = n0 + wn * 32 + j * 16 + col;
    const float bb = bias[gn];
#pragma unroll
    for (int i = 0; i < 4; ++i) {
      const int gmb = m0 + wm * 64 + i * 16 + kg * 4;
#pragma unroll
      for (int r = 0; r < 4; ++r) {
        const int gm = gmb + r;
        if (gm < M) {
          float v = acc[i][j][r] + bb;
          if (relu_f) v = fmaxf(v, 0.f);
          if (out32) ((float*)Cv)[(size_t)gm * ldc + c_off + gn] = v;
          else ((u16t*)Cv)[(size_t)gm * ldc + c_off + gn] = f2bf(v);
        }
      }
    }
  }
}

__global__ __launch_bounds__(256) void k_out(
    const float* __restrict__ h2, const float* __restrict__ Wo,
    const float* __restrict__ bo, float* __restrict__ out)
{
  __shared__ float Ws_[128];
  const int t = threadIdx.x;
  if (t < 128) Ws_[t] = Wo[t];
  __syncthreads();
  const int g = blockIdx.x * 32 + (t >> 3), l = t & 7;
  float acc = 0.f;
  if (g < NG) {
    const float* hr = h2 + (size_t)g * 128 + l * 16;
    const float* wr = Ws_ + l * 16;
#pragma unroll
    for (int j = 0; j < 16; ++j) acc = fmaf(hr[j], wr[j], acc);
  }
  acc += __shfl_down(acc, 4, 8);
  acc += __shfl_down(acc, 2, 8);
  acc += __shfl_down(acc, 1, 8);
  if (l == 0 && g < NG) out[g] = acc + bo[0];
}

extern "C" void kernel_launch(void* const* d_in, const int* in_sizes, int n_in,
                              void* d_out, int out_size, void* d_ws, size_t ws_size,
                              hipStream_t stream) {
  const float* x    = (const float*)d_in[0];
  const int*   ei   = (const int*)d_in[1];
  const int*   batch= (const int*)d_in[2];
  const float* xo   = (const float*)d_in[3];
  const float* g1W1 = (const float*)d_in[4];
  const float* g1b1 = (const float*)d_in[5];
  const float* g1W2 = (const float*)d_in[6];
  const float* g1b2 = (const float*)d_in[7];
  const float* gsW1 = (const float*)d_in[8];
  const float* gsb1 = (const float*)d_in[9];
  const float* gsW2 = (const float*)d_in[10];
  const float* gsb2 = (const float*)d_in[11];
  const float* bng  = (const float*)d_in[12];
  const float* bnb  = (const float*)d_in[13];
  const float* Wxd  = (const float*)d_in[14];
  const float* bxd  = (const float*)d_in[15];
  const float* c1W  = (const float*)d_in[16];
  const float* c1b  = (const float*)d_in[17];
  const float* c2W  = (const float*)d_in[18];
  const float* c2b  = (const float*)d_in[19];
  const float* c3W  = (const float*)d_in[20];
  const float* c3b  = (const float*)d_in[21];
  const float* Wxt  = (const float*)d_in[22];
  const float* bxt  = (const float*)d_in[23];
  const float* W1f  = (const float*)d_in[24];
  const float* b1f  = (const float*)d_in[25];
  const float* W2f  = (const float*)d_in[26];
  const float* b2f  = (const float*)d_in[27];
  const float* Wo   = (const float*)d_in[28];
  const float* bo   = (const float*)d_in[29];

  char* ws = (char*)d_ws;
  u16t*  U    = (u16t*)(ws + OFF_U);
  u16t*  YA   = (u16t*)(ws + OFF_YA);
  u16t*  YB   = (u16t*)(ws + OFF_YB);
  float* ST   = (float*)(ws + OFF_ST);
  u32t*  RS   = (u32t*)(ws + OFF_RS);
  u32t*  CUR  = (u32t*)(ws + OFF_CUR);
  u32t*  BS   = (u32t*)(ws + OFF_BSUM);
  int*   SSRC = (int*)(ws + OFF_SSRC);
  u16t*  WK   = (u16t*)(ws + OFF_WK);
  u16t*  W2K  = WK;
  u16t*  W3K  = WK + 16384;
  u16t*  WXT  = WK + 16384 + 65536;
  u16t*  WF1  = WK + 16384 + 65536 + 376832;
  u16t*  WF2  = WK + 16384 + 65536 + 376832 + 262144;
  u16t*  XC   = (u16t*)(ws + OFF_XC);
  u16t*  T3   = (u16t*)(ws + OFF_T3);
  u16t*  H1   = (u16t*)(ws + OFF_H1);
  float* H2   = (float*)(ws + OFF_H2);
  float* OUT  = (float*)d_out;

  const int NBLK = (NN + 1023) / 1024;

  hipMemsetAsync(ST, 0, 5 * 64 * sizeof(float), stream);
  hipMemsetAsync(CUR, 0, NN * sizeof(u32t), stream);

  k_prep<<<(128 * 2944 + 255) / 256, 256, 0, stream>>>(c2W, c3W, Wxt, W1f, W2f,
                                                        W2K, W3K, WXT, WF1, WF2);

  k_hist<<<(NE + 255) / 256, 256, 0, stream>>>(ei, CUR);
  k_scan1<<<NBLK, 256, 0, stream>>>(CUR, BS);
  k_scan2<<<1, 256, 0, stream>>>(BS, RS, NBLK);
  k_scan3<<<NBLK, 256, 0, stream>>>(CUR, RS, BS);
  for (int p = 0; p < 8; ++p)
    k_scatter<<<(NE + 255) / 256, 256, 0, stream>>>(ei, CUR, SSRC, p);

  k_mlp1_first<<<NN / 64, 256, 0, stream>>>(x, g1W1, U);

  // agg0 fused with CNN chunk 0 (U no longer under T3)
  k_fused0<<<20625, 256, 0, stream>>>(U, RS, SSRC, g1b1, g1W2, g1b2, YA, ST + 0,
                                      xo, c1W, c1b, W2K, c2b, W3K, c3b, T3, 0);

  // layers 1..4 fused with CNN chunks 1..4 (5000 graphs each)
  const u16t* yin = YA;
  u16t* yout = YB;
  for (int lyr = 1; lyr <= 4; ++lyr) {
    k_fused<<<20625, 256, 0, stream>>>(yin, RS, SSRC, ST + (lyr - 1) * 64,
                                       bng + (lyr - 1) * 32, bnb + (lyr - 1) * 32,
                                       gsW1 + (lyr - 1) * 1024, gsb1 + (lyr - 1) * 32,
                                       gsW2 + (lyr - 1) * 1024, gsb2 + (lyr - 1) * 32,
                                       yout, ST + lyr * 64,
                                       xo, c1W, c1b, W2K, c2b, W3K, c3b, T3,
                                       lyr * 5000);
    const u16t* tmp = yin;
    yin = yout;
    yout = (u16t*)tmp;
  }
  // yin == YA after 4 layers
  k_pool_xd<<<NG, 64, 0, stream>>>(yin, batch, ST, bng, bnb, Wxd, bxd, XC);

  {
    dim3 grid((NG + 127) / 128, 2);
    k_mgemm<<<grid, 256, 0, stream>>>(T3, 2944, WXT, bxt, XC, 256, 128, NG, 2944, 0, 0);
  }
  {
    dim3 grid((NG + 127) / 128, 16);
    k_mgemm<<<grid, 256, 0, stream>>>(XC, 256, WF1, b1f, H1, 1024, 0, NG, 256, 1, 0);
  }
  {
    dim3 grid((NG + 127) / 128, 2);
    k_mgemm<<<grid, 256, 0, stream>>>(H1, 1024, WF2, b2f, H2, 128, 0, NG, 1024, 1, 1);
  }
  k_out<<<(NG + 31) / 32, 256, 0, stream>>>(H2, Wo, bo, OUT);
}

// Round 20
// 1933.468 us; speedup vs baseline: 1.1193x; 1.0101x over previous
//
#include <hip/hip_runtime.h>

#define NN 1000000
#define NE 4000000
#define NG 25000
#define BN_EPS 1e-5f

typedef unsigned short u16t;
typedef unsigned int u32t;
typedef __attribute__((ext_vector_type(8))) short bf16x8;
typedef __attribute__((ext_vector_type(8))) _Float16 f16x8;
typedef __attribute__((ext_vector_type(4))) float f32x4;

__device__ inline u16t f2bf(float f) {
  u32t u = __float_as_uint(f);
  u32t r = (u + 0x7FFFu + ((u >> 16) & 1u)) >> 16;
  return (u16t)r;
}
__device__ inline float bf2f(u16t h) { return __uint_as_float((u32t)h << 16); }
__device__ inline u16t f2h(float f) {
  _Float16 h = (_Float16)f;
  return *(u16t*)&h;
}
__device__ inline float h2f(u16t v) {
  _Float16 h = *(_Float16*)&v;
  return (float)h;
}
__device__ inline void add8h(float* a, uint4 v) {
  union { uint4 u; _Float16 h[8]; } cv;
  cv.u = v;
#pragma unroll
  for (int j = 0; j < 8; ++j) a[j] += (float)cv.h[j];
}

// ---- workspace layout (bytes) ----
static const size_t OFF_T3   = 0;
static const size_t OFF_YA   = 150000000;
static const size_t OFF_YB   = 214000000;
static const size_t OFF_ST   = 278000000;
static const size_t OFF_RS   = 279000000;
static const size_t OFF_CUR  = 283200000;
static const size_t OFF_BSUM = 287300000;
static const size_t OFF_SSRC = 288000000;
static const size_t OFF_WK   = 304000000;
static const size_t OFF_XC   = 306000000;
static const size_t OFF_U    = 320000000;
static const size_t OFF_H1   = 150000000;
static const size_t OFF_H2   = 214000000;

// ---------------- CSR build ----------------
__global__ __launch_bounds__(256) void k_scan1(const u32t* __restrict__ deg, u32t* __restrict__ bsum) {
  __shared__ u32t red[4];
  const int b = blockIdx.x, t = threadIdx.x;
  u32t s = 0;
#pragma unroll
  for (int j = 0; j < 4; ++j) {
    const int i = b * 1024 + j * 256 + t;
    if (i < NN) s += deg[i];
  }
#pragma unroll
  for (int off = 32; off > 0; off >>= 1) s += __shfl_down(s, off);
  if ((t & 63) == 0) red[t >> 6] = s;
  __syncthreads();
  if (t == 0) bsum[b] = red[0] + red[1] + red[2] + red[3];
}

__global__ __launch_bounds__(256) void k_scan2(u32t* __restrict__ bsum, u32t* __restrict__ rs, int nblk) {
  __shared__ u32t sh[256];
  const int t = threadIdx.x;
  u32t v[4];
#pragma unroll
  for (int j = 0; j < 4; ++j) {
    const int i = t * 4 + j;
    v[j] = (i < nblk) ? bsum[i] : 0u;
  }
  const u32t tot = v[0] + v[1] + v[2] + v[3];
  sh[t] = tot;
  __syncthreads();
  for (int off = 1; off < 256; off <<= 1) {
    u32t add = (t >= off) ? sh[t - off] : 0u;
    __syncthreads();
    sh[t] += add;
    __syncthreads();
  }
  const u32t tb = (t == 0) ? 0u : sh[t - 1];
  u32t run = tb;
#pragma unroll
  for (int j = 0; j < 4; ++j) {
    const int i = t * 4 + j;
    if (i < nblk) bsum[i] = run;
    run += v[j];
  }
  if (t == 0) rs[NN] = NE;
}

__global__ __launch_bounds__(256) void k_scan3(u32t* __restrict__ cur, u32t* __restrict__ rs,
                                               const u32t* __restrict__ bsum) {
  __shared__ u32t sh[256];
  const int b = blockIdx.x, t = threadIdx.x;
  const int i0 = b * 1024 + t * 4;
  u32t v[4];
#pragma unroll
  for (int j = 0; j < 4; ++j) v[j] = (i0 + j < NN) ? cur[i0 + j] : 0u;
  sh[t] = v[0] + v[1] + v[2] + v[3];
  __syncthreads();
  for (int off = 1; off < 256; off <<= 1) {
    u32t add = (t >= off) ? sh[t - off] : 0u;
    __syncthreads();
    sh[t] += add;
    __syncthreads();
  }
  u32t run = bsum[b] + ((t == 0) ? 0u : sh[t - 1]);
#pragma unroll
  for (int j = 0; j < 4; ++j) {
    const int i = i0 + j;
    if (i < NN) { rs[i] = run; cur[i] = run; }
    run += v[j];
  }
}

// dst-range-partitioned scatter: pass p handles dst>>17 == p (8 passes).
__global__ __launch_bounds__(256) void k_scatter(const int* __restrict__ ei,
                                                 u32t* __restrict__ cur, int* __restrict__ ssrc,
                                                 int pass) {
  const int i = blockIdx.x * 256 + threadIdx.x;
  if (i < NE) {
    const int dst = ei[NE + i];
    if ((dst >> 17) == pass) {
      const int src = ei[i];
      const u32t pos = atomicAdd(&cur[dst], 1u);
      ssrc[pos] = src;
    }
  }
}

// ---------------- GNN kernels ----------------

// mlp1 body: u = x @ W1 (78->32) via fp16 MFMA, 64 nodes
__device__ __forceinline__ void mlp1_body(
    int bid, char* smem,
    const float* __restrict__ x, const float* __restrict__ W1, u16t* __restrict__ u)
{
  u16t* Xh = (u16t*)smem;               // 64*104*2 = 13312
  u16t* Wt = (u16t*)(smem + 13312);     // 32*104*2 = 6656
  u16t* Uh = (u16t*)(smem + 19968);     // 64*40*2  = 5120
  const int t = threadIdx.x;
  const int n0b = bid * 64;
  for (int id = t; id < 64 * 78; id += 256) {
    const int row = id / 78, k = id - row * 78;
    Xh[row * 104 + k] = f2h(x[(size_t)n0b * 78 + id]);
  }
  for (int id = t; id < 64 * 18; id += 256) {
    const int row = id / 18, k = 78 + (id - row * 18);
    Xh[row * 104 + k] = 0;
  }
  for (int id = t; id < 78 * 32; id += 256) {
    const int k = id >> 5, c = id & 31;
    Wt[c * 104 + k] = f2h(W1[id]);
  }
  for (int id = t; id < 32 * 18; id += 256) {
    const int c = id / 18, k = 78 + (id - c * 18);
    Wt[c * 104 + k] = 0;
  }
  __syncthreads();
  {
    const int w = t >> 6, l = t & 63, col = l & 15, kg = l >> 4;
    const int m0 = w * 16;
    f32x4 ac0 = {0.f, 0.f, 0.f, 0.f}, ac1 = {0.f, 0.f, 0.f, 0.f};
#pragma unroll
    for (int ks = 0; ks < 3; ++ks) {
      const f16x8 af = *(const f16x8*)(Xh + (m0 + col) * 104 + ks * 32 + kg * 8);
      const f16x8 bf0 = *(const f16x8*)(Wt + col * 104 + ks * 32 + kg * 8);
      const f16x8 bf1 = *(const f16x8*)(Wt + (16 + col) * 104 + ks * 32 + kg * 8);
      ac0 = __builtin_amdgcn_mfma_f32_16x16x32_f16(af, bf0, ac0, 0, 0, 0);
      ac1 = __builtin_amdgcn_mfma_f32_16x16x32_f16(af, bf1, ac1, 0, 0, 0);
    }
#pragma unroll
    for (int r = 0; r < 4; ++r) {
      const int m = m0 + kg * 4 + r;
      Uh[m * 40 + col] = f2h(ac0[r]);
      Uh[m * 40 + 16 + col] = f2h(ac1[r]);
    }
  }
  __syncthreads();
  {
    const int row = t >> 2;
    const uint4 v = *(const uint4*)(Uh + row * 40 + (t & 3) * 8);
    *(uint4*)(u + (size_t)(n0b + row) * 32 + (t & 3) * 8) = v;
  }
}

// fused hist (latency-bound atomics) + mlp1 (MFMA): grid 31250, odd=hist even=mlp1
__global__ __launch_bounds__(256) void k_hist_mlp1(
    const int* __restrict__ ei, u32t* __restrict__ cnt,
    const float* __restrict__ x, const float* __restrict__ W1, u16t* __restrict__ u)
{
  __shared__ __align__(16) char smem[25088];
  const int bid = blockIdx.x;
  if (bid & 1) {
    const int i = (bid >> 1) * 256 + threadIdx.x;
    if (i < NE) atomicAdd(&cnt[ei[NE + i]], 1u);
  } else {
    mlp1_body(bid >> 1, smem, x, W1, u);
  }
}

// ---- agg0 body (layer 0 part B), shared LDS arena ----
__device__ __forceinline__ void agg0_body(
    int bid, char* smem,
    const u16t* __restrict__ u, const u32t* __restrict__ rs, const int* __restrict__ ssrc,
    const float* __restrict__ b1, const float* __restrict__ W2, const float* __restrict__ b2,
    u16t* __restrict__ yout, float* __restrict__ stats_out)
{
  u16t* W2t = (u16t*)(smem + 2560);
  u16t* A1h = (u16t*)(smem + 5120);
  u16t* A2h = (u16t*)(smem + 10240);
  float* red = (float*)(smem + 15360);
  u32t* rss = (u32t*)(smem + 16384);
  const int t = threadIdx.x;
  const int n0b = bid * 64;
  for (int id = t; id < 1024; id += 256) {
    int k = id >> 5, c = id & 31;
    W2t[c * 40 + k] = f2h(W2[id]);
  }
  if (t < 65) rss[t] = rs[n0b + t];
  __syncthreads();
  const int nl = t >> 2, c0 = (t & 3) * 8;
  {
    const int n = n0b + nl;
    float a[8] = {};
    add8h(a, *(const uint4*)(u + (size_t)n * 32 + c0));
    const u32t e0 = rss[nl], e1 = rss[nl + 1];
    u32t e = e0;
    for (; e + 4 <= e1; e += 4) {
      const int s0v = ssrc[e], s1v = ssrc[e + 1], s2v = ssrc[e + 2], s3v = ssrc[e + 3];
      const uint4 v0 = *(const uint4*)(u + (size_t)s0v * 32 + c0);
      const uint4 v1 = *(const uint4*)(u + (size_t)s1v * 32 + c0);
      const uint4 v2 = *(const uint4*)(u + (size_t)s2v * 32 + c0);
      const uint4 v3 = *(const uint4*)(u + (size_t)s3v * 32 + c0);
      add8h(a, v0); add8h(a, v1); add8h(a, v2); add8h(a, v3);
    }
    for (; e < e1; ++e)
      add8h(a, *(const uint4*)(u + (size_t)ssrc[e] * 32 + c0));
    union { u16t h[8]; uint4 v; } pk;
#pragma unroll
    for (int j = 0; j < 8; ++j) pk.h[j] = f2h(fmaxf(a[j] + b1[c0 + j], 0.f));
    *(uint4*)(A1h + nl * 40 + c0) = pk.v;
  }
  __syncthreads();
  {
    const int w = t >> 6, l = t & 63, col = l & 15, kg = l >> 4;
    const int m0 = w * 16;
    const f16x8 af = *(const f16x8*)(A1h + (m0 + col) * 40 + kg * 8);
    const f16x8 bf0 = *(const f16x8*)(W2t + col * 40 + kg * 8);
    const f16x8 bf1 = *(const f16x8*)(W2t + (16 + col) * 40 + kg * 8);
    f32x4 ac0 = {0.f, 0.f, 0.f, 0.f}, ac1 = {0.f, 0.f, 0.f, 0.f};
    ac0 = __builtin_amdgcn_mfma_f32_16x16x32_f16(af, bf0, ac0, 0, 0, 0);
    ac1 = __builtin_amdgcn_mfma_f32_16x16x32_f16(af, bf1, ac1, 0, 0, 0);
    const float bb0 = b2[col], bb1 = b2[16 + col];
#pragma unroll
    for (int r = 0; r < 4; ++r) {
      const int m = m0 + kg * 4 + r;
      A2h[m * 40 + col] = f2h(fmaxf(ac0[r] + bb0, 0.f));
      A2h[m * 40 + 16 + col] = f2h(fmaxf(ac1[r] + bb1, 0.f));
    }
  }
  __syncthreads();
  const int c = t & 31;
  float rsum = 0.f, rq = 0.f;
#pragma unroll
  for (int rep = 0; rep < 8; ++rep) {
    const int row = (t >> 5) + rep * 8;
    const float v = h2f(A2h[row * 40 + c]);
    rsum += v;
    rq += v * v;
  }
  {
    const int row = t >> 2;
    const uint4 v = *(const uint4*)(A2h + row * 40 + (t & 3) * 8);
    *(uint4*)(yout + (size_t)(n0b + row) * 32 + (t & 3) * 8) = v;
  }
  rsum += __shfl_down(rsum, 32);
  rq += __shfl_down(rq, 32);
  __syncthreads();
  const int wv_ = t >> 6, lane = t & 63;
  if (lane < 32) {
    red[wv_ * 32 + lane] = rsum;
    red[128 + wv_ * 32 + lane] = rq;
  }
  __syncthreads();
  if (t < 32) {
    float aa = red[t] + red[32 + t] + red[64 + t] + red[96 + t];
    float bb = red[128 + t] + red[160 + t] + red[192 + t] + red[224 + t];
    unsafeAtomicAdd(&stats_out[t], aa);
    unsafeAtomicAdd(&stats_out[32 + t], bb);
  }
}

// ---- layer body (layers 1..4) ----
__device__ __forceinline__ void layer_body(
    int bid, char* smem,
    const u16t* __restrict__ yin, const u32t* __restrict__ rs, const int* __restrict__ ssrc,
    const float* __restrict__ stats, const float* __restrict__ gamma, const float* __restrict__ beta,
    const float* __restrict__ W1, const float* __restrict__ b1,
    const float* __restrict__ W2, const float* __restrict__ b2,
    u16t* __restrict__ yout, float* __restrict__ stats_out)
{
  u16t* W1t = (u16t*)smem;
  u16t* W2t = (u16t*)(smem + 2560);
  u16t* A1h = (u16t*)(smem + 5120);
  u16t* A2h = (u16t*)(smem + 10240);
  float* red = (float*)(smem + 15360);
  u32t* rss = (u32t*)(smem + 16384);
  const int t = threadIdx.x;
  const int n0b = bid * 64;
  for (int id = t; id < 1024; id += 256) {
    int k = id >> 5, c = id & 31;
    W1t[c * 40 + k] = f2h(W1[id]);
    W2t[c * 40 + k] = f2h(W2[id]);
  }
  if (t < 65) rss[t] = rs[n0b + t];
  __syncthreads();
  const int nl = t >> 2, c0 = (t & 3) * 8;
  {
    const int n = n0b + nl;
    float sc[8], sh[8];
#pragma unroll
    for (int j = 0; j < 8; ++j) {
      const int c = c0 + j;
      const float mu = stats[c] * (1.f / NN);
      float var = fmaxf(stats[32 + c] * (1.f / NN) - mu * mu, 0.f);
      sc[j] = gamma[c] * rsqrtf(var + BN_EPS);
      sh[j] = beta[c] - mu * sc[j];
    }
    float a[8] = {};
    add8h(a, *(const uint4*)(yin + (size_t)n * 32 + c0));
    const u32t e0 = rss[nl], e1 = rss[nl + 1];
    u32t e = e0;
    for (; e + 4 <= e1; e += 4) {
      const int s0v = ssrc[e], s1v = ssrc[e + 1], s2v = ssrc[e + 2], s3v = ssrc[e + 3];
      const uint4 v0 = *(const uint4*)(yin + (size_t)s0v * 32 + c0);
      const uint4 v1 = *(const uint4*)(yin + (size_t)s1v * 32 + c0);
      const uint4 v2 = *(const uint4*)(yin + (size_t)s2v * 32 + c0);
      const uint4 v3 = *(const uint4*)(yin + (size_t)s3v * 32 + c0);
      add8h(a, v0); add8h(a, v1); add8h(a, v2); add8h(a, v3);
    }
    for (; e < e1; ++e)
      add8h(a, *(const uint4*)(yin + (size_t)ssrc[e] * 32 + c0));
    const float cnt = (float)(e1 - e0 + 1u);
    union { u16t h[8]; uint4 v; } pk;
#pragma unroll
    for (int j = 0; j < 8; ++j) pk.h[j] = f2h(sc[j] * a[j] + cnt * sh[j]);
    *(uint4*)(A1h + nl * 40 + c0) = pk.v;
  }
  __syncthreads();
  const int w = t >> 6, l = t & 63, col = l & 15, kg = l >> 4;
  const int m0 = w * 16;
  {
    const f16x8 af = *(const f16x8*)(A1h + (m0 + col) * 40 + kg * 8);
    const f16x8 bf0 = *(const f16x8*)(W1t + col * 40 + kg * 8);
    const f16x8 bf1 = *(const f16x8*)(W1t + (16 + col) * 40 + kg * 8);
    f32x4 ac0 = {0.f, 0.f, 0.f, 0.f}, ac1 = {0.f, 0.f, 0.f, 0.f};
    ac0 = __builtin_amdgcn_mfma_f32_16x16x32_f16(af, bf0, ac0, 0, 0, 0);
    ac1 = __builtin_amdgcn_mfma_f32_16x16x32_f16(af, bf1, ac1, 0, 0, 0);
    const float bb0 = b1[col], bb1 = b1[16 + col];
#pragma unroll
    for (int r = 0; r < 4; ++r) {
      const int m = m0 + kg * 4 + r;
      A2h[m * 40 + col] = f2h(fmaxf(ac0[r] + bb0, 0.f));
      A2h[m * 40 + 16 + col] = f2h(fmaxf(ac1[r] + bb1, 0.f));
    }
  }
  __syncthreads();
  {
    const f16x8 af = *(const f16x8*)(A2h + (m0 + col) * 40 + kg * 8);
    const f16x8 bf0 = *(const f16x8*)(W2t + col * 40 + kg * 8);
    const f16x8 bf1 = *(const f16x8*)(W2t + (16 + col) * 40 + kg * 8);
    f32x4 ac0 = {0.f, 0.f, 0.f, 0.f}, ac1 = {0.f, 0.f, 0.f, 0.f};
    ac0 = __builtin_amdgcn_mfma_f32_16x16x32_f16(af, bf0, ac0, 0, 0, 0);
    ac1 = __builtin_amdgcn_mfma_f32_16x16x32_f16(af, bf1, ac1, 0, 0, 0);
    const float bb0 = b2[col], bb1 = b2[16 + col];
#pragma unroll
    for (int r = 0; r < 4; ++r) {
      const int m = m0 + kg * 4 + r;
      A1h[m * 40 + col] = f2h(fmaxf(ac0[r] + bb0, 0.f));
      A1h[m * 40 + 16 + col] = f2h(fmaxf(ac1[r] + bb1, 0.f));
    }
  }
  __syncthreads();
  const int c = t & 31;
  float rsum = 0.f, rq = 0.f;
#pragma unroll
  for (int rep = 0; rep < 8; ++rep) {
    const int row = (t >> 5) + rep * 8;
    const float v = h2f(A1h[row * 40 + c]);
    rsum += v;
    rq += v * v;
  }
  {
    const int row = t >> 2;
    const uint4 v = *(const uint4*)(A1h + row * 40 + (t & 3) * 8);
    *(uint4*)(yout + (size_t)(n0b + row) * 32 + (t & 3) * 8) = v;
  }
  rsum += __shfl_down(rsum, 32);
  rq += __shfl_down(rq, 32);
  __syncthreads();
  const int wv_ = t >> 6, lane = t & 63;
  if (lane < 32) {
    red[wv_ * 32 + lane] = rsum;
    red[128 + wv_ * 32 + lane] = rq;
  }
  __syncthreads();
  if (t < 32) {
    float aa = red[t] + red[32 + t] + red[64 + t] + red[96 + t];
    float bb = red[128 + t] + red[160 + t] + red[192 + t] + red[224 + t];
    unsafeAtomicAdd(&stats_out[t], aa);
    unsafeAtomicAdd(&stats_out[32 + t], bb);
  }
}

// ---- CNN body ----
__device__ __forceinline__ void cnn_body(
    int g, char* smem,
    const float* __restrict__ xo,
    const float* __restrict__ w1, const float* __restrict__ b1,
    const u16t* __restrict__ W2k, const float* __restrict__ b2,
    const u16t* __restrict__ W3k, const float* __restrict__ b3,
    u16t* __restrict__ t3)
{
  float* xot = (float*)(smem);
  float* w1s = (float*)(smem + 3072);
  float* b2s = (float*)(smem + 4096);
  float* b3s = (float*)(smem + 4352);
  short* T1T = (short*)(smem + 4864);
  char*  T2B = smem + 20736;
  u16t*  stg = (u16t*)(smem + 4864);

  const int t = threadIdx.x;
  const int w = t >> 6, l = t & 63, col = l & 15, kg = l >> 4;

  for (int i = t; i < 768; i += 256) xot[i] = (i < 735) ? xo[(size_t)g * 735 + i] : 0.f;
  w1s[t] = w1[t];
  if (t < 64) b2s[t] = b2[t];
  if (t < 128) b3s[t] = b3[t];
  if (t < 192) {
    int r = 242 + (t >> 5), c = t & 31;
    T1T[r * 32 + c] = 0;
  }
  __syncthreads();

  {
    const int c = t >> 3, qg = t & 7;
    float wv[8];
#pragma unroll
    for (int j = 0; j < 8; ++j) wv[j] = w1s[c * 8 + j];
    const float bias = b1[c];
    const int q0 = qg * 31, qe = (q0 + 31 < 242) ? q0 + 31 : 242;
#pragma unroll 1
    for (int qc = q0; qc < qe; qc += 10) {
      const int cnt = (qe - qc < 10) ? qe - qc : 10;
      float xv[37];
#pragma unroll
      for (int j = 0; j < 37; ++j) xv[j] = xot[3 * qc + j];
#pragma unroll
      for (int j0 = 0; j0 < 10; ++j0) {
        if (j0 < cnt) {
          float a0 = bias, a1 = bias, a2 = bias;
#pragma unroll
          for (int tt = 0; tt < 8; ++tt) {
            a0 = fmaf(wv[tt], xv[3 * j0 + tt], a0);
            a1 = fmaf(wv[tt], xv[3 * j0 + 1 + tt], a1);
            a2 = fmaf(wv[tt], xv[3 * j0 + 2 + tt], a2);
          }
          float m = fmaxf(fmaxf(a0, a1), fmaxf(a2, 0.f));
          const int pos = qc + j0;
          T1T[pos * 32 + (c ^ ((pos & 3) << 3))] = (short)f2bf(m);
        }
      }
    }
  }
  __syncthreads();

  {
    bf16x8 am[8];
#pragma unroll
    for (int kk = 0; kk < 8; ++kk)
      am[kk] = *(const bf16x8*)(W2k + (w * 16 + col) * 256 + kk * 32 + kg * 8);
#pragma unroll 1
    for (int qt = 0; qt < 5; ++qt) {
      const int rbase = qt * 48 + col * 3;
      bf16x8 rv[10];
#pragma unroll
      for (int s = 0; s < 10; ++s) {
        const int row = rbase + s;
        rv[s] = *(const bf16x8*)(T1T + row * 32 + ((kg ^ (row & 3)) << 3));
      }
      f32x4 a0 = {0.f, 0.f, 0.f, 0.f}, a1 = a0, a2 = a0;
#pragma unroll
      for (int kk = 0; kk < 8; ++kk) {
        a0 = __builtin_amdgcn_mfma_f32_16x16x32_bf16(am[kk], rv[kk], a0, 0, 0, 0);
        a1 = __builtin_amdgcn_mfma_f32_16x16x32_bf16(am[kk], rv[kk + 1], a1, 0, 0, 0);
        a2 = __builtin_amdgcn_mfma_f32_16x16x32_bf16(am[kk], rv[kk + 2], a2, 0, 0, 0);
      }
      const int q = qt * 16 + col;
      if (q < 78) {
        union { u16t u[4]; uint2 v; } pk;
#pragma unroll
        for (int r = 0; r < 4; ++r) {
          const float bb = b2s[w * 16 + kg * 4 + r];
          float m = fmaxf(fmaxf(a0[r], a1[r]), a2[r]);
          pk.u[r] = f2bf(fmaxf(m + bb, 0.f));
        }
        const int boff = (q * 128 + (w * 16 + kg * 4) * 2) ^ ((q & 7) << 4);
        *(uint2*)(T2B + boff) = pk.v;
      }
    }
  }
  __syncthreads();

  {
#pragma unroll 1
    for (int mi = 0; mi < 2; ++mi) {
      const int m3 = w * 2 + mi;
      f32x4 acc[2][3];
#pragma unroll
      for (int qt = 0; qt < 2; ++qt)
#pragma unroll
        for (int r = 0; r < 3; ++r) acc[qt][r] = (f32x4){0.f, 0.f, 0.f, 0.f};
#pragma unroll 1
      for (int kh = 0; kh < 2; ++kh) {
        bf16x8 amh[8];
#pragma unroll
        for (int tt = 0; tt < 8; ++tt)
          amh[tt] = *(const bf16x8*)(W3k + (m3 * 16 + col) * 512 + (tt * 2 + kh) * 32 + kg * 8);
#pragma unroll
        for (int qt = 0; qt < 2; ++qt) {
          const int rbase = qt * 48 + col * 3;
          bf16x8 rv[10];
#pragma unroll
          for (int s = 0; s < 10; ++s) {
            int row = rbase + s;
            row = (row < 78) ? row : 77;
            const int boff = (row * 128 + kh * 64 + kg * 16) ^ ((row & 7) << 4);
            rv[s] = *(const bf16x8*)(T2B + boff);
          }
#pragma unroll
          for (int tt = 0; tt < 8; ++tt) {
            acc[qt][0] = __builtin_amdgcn_mfma_f32_16x16x32_bf16(amh[tt], rv[tt], acc[qt][0], 0, 0, 0);
            acc[qt][1] = __builtin_amdgcn_mfma_f32_16x16x32_bf16(amh[tt], rv[tt + 1], acc[qt][1], 0, 0, 0);
            acc[qt][2] = __builtin_amdgcn_mfma_f32_16x16x32_bf16(amh[tt], rv[tt + 2], acc[qt][2], 0, 0, 0);
          }
        }
      }
#pragma unroll
      for (int qt = 0; qt < 2; ++qt) {
        const int q = qt * 16 + col;
        if (q < 23) {
#pragma unroll
          for (int r = 0; r < 4; ++r) {
            const int c = m3 * 16 + kg * 4 + r;
            float m = fmaxf(fmaxf(acc[qt][0][r], acc[qt][1][r]), acc[qt][2][r]);
            stg[c * 23 + q] = f2bf(fmaxf(m + b3s[c], 0.f));
          }
        }
      }
    }
  }
  __syncthreads();

  {
    const uint4* s4 = (const uint4*)stg;
    uint4* d4 = (uint4*)(t3 + (size_t)g * 2944);
    for (int id = t; id < 368; id += 256) d4[id] = s4[id];
  }
}

// ---- fused agg0 + CNN chunk: 25 agg blocks + 8 cnn blocks per group of 33 ----
__global__ __launch_bounds__(256, 4) void k_fused0(
    const u16t* __restrict__ u, const u32t* __restrict__ rs, const int* __restrict__ ssrc,
    const float* __restrict__ b1, const float* __restrict__ W2, const float* __restrict__ b2,
    u16t* __restrict__ yout, float* __restrict__ stats_out,
    const float* __restrict__ xo, const float* __restrict__ c1W, const float* __restrict__ c1b,
    const u16t* __restrict__ W2k, const float* __restrict__ c2b,
    const u16t* __restrict__ W3k, const float* __restrict__ c3b,
    u16t* __restrict__ t3, int cnn_g0)
{
  __shared__ __align__(16) char smem[30720];
  const int grp = blockIdx.x / 33, rem = blockIdx.x % 33;
  if (rem < 25)
    agg0_body(grp * 25 + rem, smem, u, rs, ssrc, b1, W2, b2, yout, stats_out);
  else
    cnn_body(cnn_g0 + grp * 8 + (rem - 25), smem, xo, c1W, c1b, W2k, c2b, W3k, c3b, t3);
}

// ---- fused layer + CNN chunk: 25 layer blocks + 8 cnn blocks per group of 33 ----
__global__ __launch_bounds__(256, 4) void k_fused(
    const u16t* __restrict__ yin, const u32t* __restrict__ rs, const int* __restrict__ ssrc,
    const float* __restrict__ stats, const float* __restrict__ gamma, const float* __restrict__ beta,
    const float* __restrict__ W1, const float* __restrict__ b1,
    const float* __restrict__ W2, const float* __restrict__ b2,
    u16t* __restrict__ yout, float* __restrict__ stats_out,
    const float* __restrict__ xo, const float* __restrict__ c1W, const float* __restrict__ c1b,
    const u16t* __restrict__ W2k, const float* __restrict__ c2b,
    const u16t* __restrict__ W3k, const float* __restrict__ c3b,
    u16t* __restrict__ t3, int cnn_g0)
{
  __shared__ __align__(16) char smem[30720];
  const int grp = blockIdx.x / 33, rem = blockIdx.x % 33;
  if (rem < 25)
    layer_body(grp * 25 + rem, smem, yin, rs, ssrc, stats, gamma, beta,
               W1, b1, W2, b2, yout, stats_out);
  else
    cnn_body(cnn_g0 + grp * 8 + (rem - 25), smem, xo, c1W, c1b, W2k, c2b, W3k, c3b, t3);
}

// ---- pool body: 4 graphs per 256-thread block ----
__device__ __forceinline__ void pool4_body(
    int pb, char* smem,
    const u16t* __restrict__ y, const int* __restrict__ batch,
    const float* __restrict__ stats, const float* __restrict__ gamma,
    const float* __restrict__ beta, const float* __restrict__ Wxd,
    const float* __restrict__ bxd, u16t* __restrict__ xc)
{
  float* pl = (float*)smem;  // [4][32]
  const int t = threadIdx.x, sg = t >> 6, tl = t & 63;
  const int g = pb * 4 + sg;
  int lo = 0, n = NN;
  while (n > 0) {
    int h = n >> 1, m = lo + h;
    if (batch[m] < g) { lo = m + 1; n -= h + 1; } else n = h;
  }
  int hi = lo;
  n = NN - lo;
  while (n > 0) {
    int h = n >> 1, m = hi + h;
    if (batch[m] < g + 1) { hi = m + 1; n -= h + 1; } else n = h;
  }
  const int c = tl & 31;
  const float mu = stats[4 * 64 + c] * (1.f / NN);
  float var = fmaxf(stats[4 * 64 + 32 + c] * (1.f / NN) - mu * mu, 0.f);
  const float sc = gamma[4 * 32 + c] * rsqrtf(var + BN_EPS);
  const float sh = beta[4 * 32 + c] - mu * sc;
  float acc = 0.f;
  for (int i = lo + (tl >> 5); i < hi; i += 2) acc += h2f(y[(size_t)i * 32 + c]);
  acc += __shfl_down(acc, 32);
  if (tl < 32) pl[sg * 32 + tl] = acc * sc + (float)(hi - lo) * sh;
  __syncthreads();
#pragma unroll
  for (int rep = 0; rep < 2; ++rep) {
    const int o = tl + rep * 64;
    float a = bxd[o];
#pragma unroll
    for (int cc = 0; cc < 32; ++cc) a = fmaf(pl[sg * 32 + cc], Wxd[cc * 128 + o], a);
    xc[(size_t)g * 256 + o] = f2bf(fmaxf(a, 0.f));
  }
}

// ---- T3 gemm body (bf16 MFMA, M=NG K=2944 -> XC cols 128..255), bx=0..195 by=0..1 ----
__device__ __forceinline__ void gemm_t3_body(
    int bx, int by, char* smem,
    const u16t* __restrict__ A, const u16t* __restrict__ WT, const float* __restrict__ bias,
    u16t* __restrict__ Cv)
{
  u16t* As = (u16t*)smem;               // 128*32*2 = 8192
  u16t* Ws2 = (u16t*)(smem + 8192);     // 64*32*2  = 4096
  const int t = threadIdx.x;
  const int w = t >> 6, l = t & 63, col = l & 15, kg = l >> 4;
  const int wm = w & 1, wn = w >> 1;
  const int m0 = bx * 128, n0 = by * 64;
  f32x4 acc[4][2];
#pragma unroll
  for (int i = 0; i < 4; ++i)
#pragma unroll
    for (int j = 0; j < 2; ++j) acc[i][j] = (f32x4){0.f, 0.f, 0.f, 0.f};
  const int ar = t >> 1, ac = (t & 1) * 2;
  const int wr = t >> 2, wc = t & 3;
  const bool aok = (m0 + ar) < NG;
  const u16t* Ap = A + (size_t)(m0 + ar) * 2944;
  const u16t* Wp = WT + (size_t)(n0 + wr) * 2944;
  for (int k0 = 0; k0 < 2944; k0 += 32) {
    bf16x8 av0 = {0, 0, 0, 0, 0, 0, 0, 0}, av1 = {0, 0, 0, 0, 0, 0, 0, 0};
    if (aok) {
      av0 = *(const bf16x8*)(Ap + k0 + ac * 8);
      av1 = *(const bf16x8*)(Ap + k0 + (ac + 1) * 8);
    }
    const bf16x8 wv = *(const bf16x8*)(Wp + k0 + wc * 8);
    __syncthreads();
    *(bf16x8*)(As + (ar * 4 + (ac ^ (ar & 3))) * 8) = av0;
    *(bf16x8*)(As + (ar * 4 + ((ac + 1) ^ (ar & 3))) * 8) = av1;
    *(bf16x8*)(Ws2 + (wr * 4 + (wc ^ (wr & 3))) * 8) = wv;
    __syncthreads();
    bf16x8 af[4], bf[2];
#pragma unroll
    for (int i = 0; i < 4; ++i) {
      const int R = wm * 64 + i * 16 + col;
      af[i] = *(const bf16x8*)(As + (R * 4 + (kg ^ (R & 3))) * 8);
    }
#pragma unroll
    for (int j = 0; j < 2; ++j) {
      const int R = wn * 32 + j * 16 + col;
      bf[j] = *(const bf16x8*)(Ws2 + (R * 4 + (kg ^ (R & 3))) * 8);
    }
#pragma unroll
    for (int i = 0; i < 4; ++i)
#pragma unroll
      for (int j = 0; j < 2; ++j)
        acc[i][j] = __builtin_amdgcn_mfma_f32_16x16x32_bf16(af[i], bf[j], acc[i][j], 0, 0, 0);
  }
#pragma unroll
  for (int j = 0; j < 2; ++j) {
    const int gn = n0 + wn * 32 + j * 16 + col;
    const float bb = bias[gn];
#pragma unroll
    for (int i = 0; i < 4; ++i) {
      const int gmb = m0 + wm * 64 + i * 16 + kg * 4;
#pragma unroll
      for (int r = 0; r < 4; ++r) {
        const int gm = gmb + r;
        if (gm < NG) Cv[(size_t)gm * 256 + 128 + gn] = f2bf(acc[i][j][r] + bb);
      }
    }
  }
}

// ---- fused pool + T3 gemm: groups of 17 = 16 pool + 1 gemm; grid 392*17 ----
__global__ __launch_bounds__(256, 4) void k_pool_gemm(
    const u16t* __restrict__ y, const int* __restrict__ batch,
    const float* __restrict__ stats, const float* __restrict__ gamma,
    const float* __restrict__ beta, const float* __restrict__ Wxd,
    const float* __restrict__ bxd, u16t* __restrict__ xc,
    const u16t* __restrict__ T3, const u16t* __restrict__ WXT,
    const float* __restrict__ bxt)
{
  __shared__ __align__(16) char smem[12800];
  const int grp = blockIdx.x / 17, rem = blockIdx.x % 17;
  if (rem < 16) {
    const int pb = grp * 16 + rem;
    if (pb >= NG / 4) return;  // uniform per block, before any barrier
    pool4_body(pb, smem, y, batch, stats, gamma, beta, Wxd, bxd, xc);
  } else {
    gemm_t3_body(grp % 196, grp / 196, smem, T3, WXT, bxt, xc);
  }
}

// ---------------- weight prep ----------------
__global__ __launch_bounds__(256) void k_prep(
    const float* __restrict__ w2, const float* __restrict__ w3,
    const float* __restrict__ wxt, const float* __restrict__ wf1, const float* __restrict__ wf2,
    u16t* __restrict__ W2k, u16t* __restrict__ W3k,
    u16t* __restrict__ WXT, u16t* __restrict__ WF1, u16t* __restrict__ WF2)
{
  const int i = blockIdx.x * 256 + threadIdx.x;
  if (i < 64 * 256) {
    int c2 = i >> 8, kk = i & 255, tt = kk >> 5, ci = kk & 31;
    W2k[i] = f2bf(w2[c2 * 256 + ci * 8 + tt]);
  }
  if (i < 128 * 512) {
    int c3 = i >> 9, kk = i & 511, tt = kk >> 6, ci = kk & 63;
    W3k[i] = f2bf(w3[c3 * 512 + ci * 8 + tt]);
  }
  if (i < 128 * 2944) {
    int nn = i / 2944, kk = i - nn * 2944;
    WXT[i] = f2bf(wxt[kk * 128 + nn]);
  }
  if (i < 1024 * 256) {
    int nn = i >> 8, kk = i & 255;
    WF1[i] = f2bf(wf1[kk * 1024 + nn]);
  }
  if (i < 128 * 1024) {
    int nn = i >> 10, kk = i & 1023;
    WF2[i] = f2bf(wf2[kk * 128 + nn]);
  }
}

// ---------------- bf16 MFMA GEMM (H1/H2 heads) ----------------
__global__ __launch_bounds__(256) void k_mgemm(
    const u16t* __restrict__ A, int lda,
    const u16t* __restrict__ WT, const float* __restrict__ bias,
    void* __restrict__ Cv, int ldc, int c_off, int M, int Kd,
    int relu_f, int out32)
{
  __shared__ __align__(16) u16t As[128 * 4 * 8];
  __shared__ __align__(16) u16t Ws2[64 * 4 * 8];
  const int t = threadIdx.x;
  const int w = t >> 6, l = t & 63, col = l & 15, kg = l >> 4;
  const int wm = w & 1, wn = w >> 1;
  const int m0 = blockIdx.x * 128, n0 = blockIdx.y * 64;
  f32x4 acc[4][2];
#pragma unroll
  for (int i = 0; i < 4; ++i)
#pragma unroll
    for (int j = 0; j < 2; ++j) acc[i][j] = (f32x4){0.f, 0.f, 0.f, 0.f};
  const int ar = t >> 1, ac = (t & 1) * 2;
  const int wr = t >> 2, wc = t & 3;
  const bool aok = (m0 + ar) < M;
  const u16t* Ap = A + (size_t)(m0 + ar) * lda;
  const u16t* Wp = WT + (size_t)(n0 + wr) * Kd;
  for (int k0 = 0; k0 < Kd; k0 += 32) {
    bf16x8 av0 = {0, 0, 0, 0, 0, 0, 0, 0}, av1 = {0, 0, 0, 0, 0, 0, 0, 0};
    if (aok) {
      av0 = *(const bf16x8*)(Ap + k0 + ac * 8);
      av1 = *(const bf16x8*)(Ap + k0 + (ac + 1) * 8);
    }
    const bf16x8 wv = *(const bf16x8*)(Wp + k0 + wc * 8);
    __syncthreads();
    *(bf16x8*)(As + (ar * 4 + (ac ^ (ar & 3))) * 8) = av0;
    *(bf16x8*)(As + (ar * 4 + ((ac + 1) ^ (ar & 3))) * 8) = av1;
    *(bf16x8*)(Ws2 + (wr * 4 + (wc ^ (wr & 3))) * 8) = wv;
    __syncthreads();
    bf16x8 af[4], bf[2];
#pragma unroll
    for (int i = 0; i < 4; ++i) {
      const int R = wm * 64 + i * 16 + col;
      af[i] = *(const bf16x8*)(As + (R * 4 + (kg ^ (R & 3))) * 8);
    }
#pragma unroll
    for (int j = 0; j < 2; ++j) {
      const int R = wn * 32 + j * 16 + col;
      bf[j] = *(const bf16x8*)(Ws2 + (R * 4 + (kg ^ (R & 3))) * 8);
    }
#pragma unroll
    for (int i = 0; i < 4; ++i)
#pragma unroll
      for (int j = 0; j < 2; ++j)
        acc[i][j] = __builtin_amdgcn_mfma_f32_16x16x32_bf16(af[i], bf[j], acc[i][j], 0, 0, 0);
  }
#pragma unroll
  for (int j = 0; j < 2; ++j) {
    const int gn = n0 + wn * 32 + j * 16 + col;
    const float bb = bias[gn];
#pragma unroll
    for (int i = 0; i < 4; ++i) {
      const int gmb = m0 + wm * 64 + i * 16 + kg * 4;
#pragma unroll
      for (int r = 0; r < 4; ++r) {
        const int gm = gmb + r;
        if (gm < M) {
          float v = acc[i][j][r] + bb;
          if (relu_f) v = fmaxf(v, 0.f);
          if (out32) ((float*)Cv)[(size_t)gm * ldc + c_off + gn] = v;
          else ((u16t*)Cv)[(size_t)gm * ldc + c_off + gn] = f2bf(v);
        }
      }
    }
  }
}

__global__ __launch_bounds__(256) void k_out(
    const float* __restrict__ h2, const float* __restrict__ Wo,
    const float* __restrict__ bo, float* __restrict__ out)
{
  __shared__ float Ws_[128];
  const int t = threadIdx.x;
  if (t < 128) Ws_[t] = Wo[t];
  __syncthreads();
  const int g = blockIdx.x * 32 + (t >> 3), l = t & 7;
  float acc = 0.f;
  if (g < NG) {
    const float* hr = h2 + (size_t)g * 128 + l * 16;
    const float* wr = Ws_ + l * 16;
#pragma unroll
    for (int j = 0; j < 16; ++j) acc = fmaf(hr[j], wr[j], acc);
  }
  acc += __shfl_down(acc, 4, 8);
  acc += __shfl_down(acc, 2, 8);
  acc += __shfl_down(acc, 1, 8);
  if (l == 0 && g < NG) out[g] = acc + bo[0];
}

extern "C" void kernel_launch(void* const* d_in, const int* in_sizes, int n_in,
                              void* d_out, int out_size, void* d_ws, size_t ws_size,
                              hipStream_t stream) {
  const float* x    = (const float*)d_in[0];
  const int*   ei   = (const int*)d_in[1];
  const int*   batch= (const int*)d_in[2];
  const float* xo   = (const float*)d_in[3];
  const float* g1W1 = (const float*)d_in[4];
  const float* g1b1 = (const float*)d_in[5];
  const float* g1W2 = (const float*)d_in[6];
  const float* g1b2 = (const float*)d_in[7];
  const float* gsW1 = (const float*)d_in[8];
  const float* gsb1 = (const float*)d_in[9];
  const float* gsW2 = (const float*)d_in[10];
  const float* gsb2 = (const float*)d_in[11];
  const float* bng  = (const float*)d_in[12];
  const float* bnb  = (const float*)d_in[13];
  const float* Wxd  = (const float*)d_in[14];
  const float* bxd  = (const float*)d_in[15];
  const float* c1W  = (const float*)d_in[16];
  const float* c1b  = (const float*)d_in[17];
  const float* c2W  = (const float*)d_in[18];
  const float* c2b  = (const float*)d_in[19];
  const float* c3W  = (const float*)d_in[20];
  const float* c3b  = (const float*)d_in[21];
  const float* Wxt  = (const float*)d_in[22];
  const float* bxt  = (const float*)d_in[23];
  const float* W1f  = (const float*)d_in[24];
  const float* b1f  = (const float*)d_in[25];
  const float* W2f  = (const float*)d_in[26];
  const float* b2f  = (const float*)d_in[27];
  const float* Wo   = (const float*)d_in[28];
  const float* bo   = (const float*)d_in[29];

  char* ws = (char*)d_ws;
  u16t*  U    = (u16t*)(ws + OFF_U);
  u16t*  YA   = (u16t*)(ws + OFF_YA);
  u16t*  YB   = (u16t*)(ws + OFF_YB);
  float* ST   = (float*)(ws + OFF_ST);
  u32t*  RS   = (u32t*)(ws + OFF_RS);
  u32t*  CUR  = (u32t*)(ws + OFF_CUR);
  u32t*  BS   = (u32t*)(ws + OFF_BSUM);
  int*   SSRC = (int*)(ws + OFF_SSRC);
  u16t*  WK   = (u16t*)(ws + OFF_WK);
  u16t*  W2K  = WK;
  u16t*  W3K  = WK + 16384;
  u16t*  WXT  = WK + 16384 + 65536;
  u16t*  WF1  = WK + 16384 + 65536 + 376832;
  u16t*  WF2  = WK + 16384 + 65536 + 376832 + 262144;
  u16t*  XC   = (u16t*)(ws + OFF_XC);
  u16t*  T3   = (u16t*)(ws + OFF_T3);
  u16t*  H1   = (u16t*)(ws + OFF_H1);
  float* H2   = (float*)(ws + OFF_H2);
  float* OUT  = (float*)d_out;

  const int NBLK = (NN + 1023) / 1024;

  hipMemsetAsync(ST, 0, 5 * 64 * sizeof(float), stream);
  hipMemsetAsync(CUR, 0, NN * sizeof(u32t), stream);

  k_prep<<<(128 * 2944 + 255) / 256, 256, 0, stream>>>(c2W, c3W, Wxt, W1f, W2f,
                                                        W2K, W3K, WXT, WF1, WF2);

  // hist (atomics, latency-bound) fused with mlp1 (MFMA) -- both input-only deps
  k_hist_mlp1<<<31250, 256, 0, stream>>>(ei, CUR, x, g1W1, U);

  k_scan1<<<NBLK, 256, 0, stream>>>(CUR, BS);
  k_scan2<<<1, 256, 0, stream>>>(BS, RS, NBLK);
  k_scan3<<<NBLK, 256, 0, stream>>>(CUR, RS, BS);
  for (int p = 0; p < 8; ++p)
    k_scatter<<<(NE + 255) / 256, 256, 0, stream>>>(ei, CUR, SSRC, p);

  // agg0 fused with CNN chunk 0
  k_fused0<<<20625, 256, 0, stream>>>(U, RS, SSRC, g1b1, g1W2, g1b2, YA, ST + 0,
                                      xo, c1W, c1b, W2K, c2b, W3K, c3b, T3, 0);

  // layers 1..4 fused with CNN chunks 1..4 (5000 graphs each)
  const u16t* yin = YA;
  u16t* yout = YB;
  for (int lyr = 1; lyr <= 4; ++lyr) {
    k_fused<<<20625, 256, 0, stream>>>(yin, RS, SSRC, ST + (lyr - 1) * 64,
                                       bng + (lyr - 1) * 32, bnb + (lyr - 1) * 32,
                                       gsW1 + (lyr - 1) * 1024, gsb1 + (lyr - 1) * 32,
                                       gsW2 + (lyr - 1) * 1024, gsb2 + (lyr - 1) * 32,
                                       yout, ST + lyr * 64,
                                       xo, c1W, c1b, W2K, c2b, W3K, c3b, T3,
                                       lyr * 5000);
    const u16t* tmp = yin;
    yin = yout;
    yout = (u16t*)tmp;
  }
  // yin == YA after 4 layers

  // pool (latency-bound) fused with T3->XC gemm (compute-bound); disjoint XC halves
  k_pool_gemm<<<392 * 17, 256, 0, stream>>>(yin, batch, ST, bng, bnb, Wxd, bxd, XC,
                                            T3, WXT, bxt);

  {
    dim3 grid((NG + 127) / 128, 16);
    k_mgemm<<<grid, 256, 0, stream>>>(XC, 256, WF1, b1f, H1, 1024, 0, NG, 256, 1, 0);
  }
  {
    dim3 grid((NG + 127) / 128, 2);
    k_mgemm<<<grid, 256, 0, stream>>>(H1, 1024, WF2, b2f, H2, 128, 0, NG, 1024, 1, 1);
  }
  k_out<<<(NG + 31) / 32, 256, 0, stream>>>(H2, Wo, bo, OUT);
}